// Round 9
// baseline (335.907 us; speedup 1.0000x reference)
//
#include <hip/hip_runtime.h>

#define NB 8
#define SL 512
#define DM 1024
#define NH 16
#define DH 64

using bfrag = __attribute__((ext_vector_type(8))) short;   // 8 bf16 (4 VGPRs)
using facc  = __attribute__((ext_vector_type(4))) float;   // 4 fp32 acc

__device__ __forceinline__ float bf2f(ushort u) {
    return __uint_as_float(((unsigned)u) << 16);
}
__device__ __forceinline__ ushort f2bf(float f) {
    unsigned x = __float_as_uint(f);
    return (ushort)((x + 0x7FFFu + ((x >> 16) & 1u)) >> 16);   // RNE
}
__device__ __forceinline__ unsigned pack2(float a, float b) {
    return (unsigned)f2bf(a) | ((unsigned)f2bf(b) << 16);
}
__device__ __forceinline__ void gload16(const ushort* g, ushort* l) {
    __builtin_amdgcn_global_load_lds(
        (const __attribute__((address_space(1))) unsigned*)g,
        (__attribute__((address_space(3))) unsigned*)l, 16, 0, 0);
}

// ---------------------------------------------------------------------------
// Transpose-convert body: W[R,C] fp32 -> WT[C,R] bf16, one 64x64 tile.
// Caller provides >= 8704 B of LDS.
// ---------------------------------------------------------------------------
__device__ __forceinline__ void tconv_body(void* smem_,
                                           const float* __restrict__ W,
                                           ushort* __restrict__ WT,
                                           const int R, const int C,
                                           const int c0, const int r0) {
    ushort (*T)[68] = (ushort (*)[68])smem_;
    const int tid = threadIdx.x;
    #pragma unroll
    for (int rr = 0; rr < 4; ++rr) {
        const int r = (tid >> 4) + rr * 16;
        const int c4 = (tid & 15) * 4;
        const float4 f = *(const float4*)(W + (size_t)(r0 + r) * C + c0 + c4);
        T[c4+0][r] = f2bf(f.x); T[c4+1][r] = f2bf(f.y);
        T[c4+2][r] = f2bf(f.z); T[c4+3][r] = f2bf(f.w);
    }
    __syncthreads();
    #pragma unroll
    for (int rr = 0; rr < 4; ++rr) {
        const int c = (tid >> 4) + rr * 16;
        const int r4 = (tid & 15) * 4;
        *(ushort4*)(WT + (size_t)(c0 + c) * R + r0 + r4) =
            make_ushort4(T[c][r4+0], T[c][r4+1], T[c][r4+2], T[c][r4+3]);
    }
}

// ---------------------------------------------------------------------------
// prep: cvt text+image (0..8191) + transpose Wq/Wk/Wv/Wo (8192..9215)
// [+ W1/W2 (9216..10239) when launched with the extended grid].
// ---------------------------------------------------------------------------
__global__ __launch_bounds__(256)
void prep_k(const float* __restrict__ text, const float* __restrict__ image,
            const float* __restrict__ Wq, const float* __restrict__ Wk,
            const float* __restrict__ Wv, const float* __restrict__ Wo,
            const float* __restrict__ W1, const float* __restrict__ W2,
            ushort* __restrict__ xbf, ushort* __restrict__ Wt,
            ushort* __restrict__ WoT, ushort* __restrict__ W1T,
            ushort* __restrict__ W2T)
{
    __shared__ ushort Tbuf[64][68];
    const int bid = blockIdx.x;
    const size_t SZc = (size_t)NB * SL * DM;
    if (bid < 8192) {
        const int half = bid >> 12;
        const float* s = half ? image : text;
        ushort* d = xbf + (size_t)half * SZc;
        const size_t i = ((size_t)(bid & 4095) * 256 + threadIdx.x) * 4;
        const float4 f = *(const float4*)(s + i);
        *(ushort4*)(d + i) =
            make_ushort4(f2bf(f.x), f2bf(f.y), f2bf(f.z), f2bf(f.w));
    } else if (bid < 9216) {
        const int t = bid - 8192;
        const int wsel = t >> 8, tt = t & 255;
        const float* W = (wsel == 0) ? Wq : (wsel == 1) ? Wk
                       : (wsel == 2) ? Wv : Wo;
        ushort* WT = (wsel < 3) ? Wt + (size_t)wsel * DM * DM : WoT;
        tconv_body(Tbuf, W, WT, DM, DM, (tt & 15) * 64, (tt >> 4) * 64);
    } else {
        const int t = bid - 9216;
        if (t < 768)
            tconv_body(Tbuf, W1, W1T, 3 * DM, DM, (t & 15) * 64, (t >> 4) * 64);
        else {
            const int u = t - 768;
            tconv_body(Tbuf, W2, W2T, DM, DM, (u & 15) * 64, (u >> 4) * 64);
        }
    }
}

// ---------------------------------------------------------------------------
// W1 [3072,1024] (blocks 0..767) + W2 [1024,1024] (768..1023) transposes.
// (fallback path only; extended path folds these into prep_k)
// ---------------------------------------------------------------------------
__global__ __launch_bounds__(256)
void tconvW12_k(const float* __restrict__ W1, const float* __restrict__ W2,
                ushort* __restrict__ W1T, ushort* __restrict__ W2T)
{
    __shared__ ushort Tbuf[64][68];
    const int bid = blockIdx.x;
    if (bid < 768)
        tconv_body(Tbuf, W1, W1T, 3 * DM, DM, (bid & 15) * 64, (bid >> 4) * 64);
    else {
        const int t = bid - 768;
        tconv_body(Tbuf, W2, W2T, DM, DM, (t & 15) * 64, (t >> 4) * 64);
    }
}

// ---------------------------------------------------------------------------
// bf16 MFMA GEMM body: 128x128 tile, WAVES in {4,8}, BK in {64,32},
// double-buffered LDS staging (one barrier per K-iter; stage(k+1) overlaps
// compute(k)).
// WAVES=4: 2x2 waves of 64x64 (acc 4x4). WAVES=8: 2x4 waves of 64x32.
// BK=64: 64 KB LDS -> 2 blocks/CU. BK=32: 32 KB LDS -> 4-5 blocks/CU —
//   the per-K-iter barrier drain (the m97-structure's ~20% stall) is then
//   hidden by 2x more co-resident blocks; K-order and MFMA sequence are
//   BIT-IDENTICAL (BK=64 already issued two K=32 steps per iter).
// BK=32 swizzle derivation: chunk = 16 rows x 32 cols; lane -> (row=lane>>2,
//   kgrp=lane&3); store key f(row)=(row>>1)&3 (uniform 2-lane/16B-slot on
//   ds_read_b128 = free tier; row&3 would be 4-way); read ch = qd^((ln>>1)&3)
//   -> logical k-group retrieved = qd, same fragment semantics as BK=64.
//   out[m,n] = ACT( sum_k A[m,k]*B[k,n] + bias[n] ),  B given as BT[n,k].
// A K-concat: A0 | A1 (bf16) | third segment = A2b (bf16) if non-null else
// A2f (fp32 load+convert). M-concat: rows >= Msplit from AM1 (block-uniform).
// XCD swizzle on logical index L. OMODE 0: fp32 row-major. 2: bf16.
// 4: fused QKV epilogue. 5: fp32 + bf16 side-copy.
// Caller provides BK*1024 bytes of LDS.
// ---------------------------------------------------------------------------
template<int ACT, int OMODE, int WAVES, int BK>
__device__ __forceinline__ void gemm_body(
    void* smem_, const int L, const int NTg, const int MTg,
    const ushort* __restrict__ A0, const ushort* __restrict__ A1,
    const float* __restrict__ A2f, const ushort* __restrict__ A2b,
    const int KA1, const int KA2, const int Ktot,
    const int lda, const int ldaf,
    const ushort* __restrict__ AM1, const int Msplit,
    const ushort* __restrict__ BT, const int ldb,
    const float* __restrict__ bias, const float* __restrict__ biasK,
    const float* __restrict__ biasV,
    float* __restrict__ outf, ushort* __restrict__ outb,
    ushort* __restrict__ outbK, ushort* __restrict__ outbVT,
    const int clustN)
{
    constexpr int NJ  = (WAVES == 4) ? 4 : 2;   // n-frags per wave
    constexpr int RPC = 512 / BK;               // rows per 1KB staging chunk
    constexpr int CHK = (128 * BK) / 512;       // chunks per A (or B) half
    constexpr int TC  = CHK / WAVES;            // chunk iters per wave
    constexpr int HBUF = 128 * BK;              // ushorts per half (A or B)
    ushort* sh = (ushort*)smem_;                // 2 x (As + Bs)
    const int tid  = threadIdx.x;
    const int w    = tid >> 6;
    const int lane = tid & 63;
    const int ln   = lane & 15, qd = lane >> 4;
    const int wm = (w & 1) * 64;
    const int wn = (WAVES == 4) ? (w >> 1) * 64 : (w >> 1) * 32;

    // ---- XCD-clustered block swizzle ----
    const int xcd = L & 7, sIdx = L >> 3;
    int mt, nt;
    if (clustN) { const int np = NTg >> 3; nt = xcd * np + sIdx % np; mt = sIdx / np; }
    else        { mt = xcd * (MTg >> 3) + sIdx / NTg; nt = sIdx - (sIdx / NTg) * NTg; }
    const int m0 = mt * 128, n0 = nt * 128;

    // ---- M-concat source select (block-uniform) ----
    const ushort* A0u = A0; const ushort* A1u = A1; int m0A = m0;
    if (Msplit && m0 >= Msplit) { A0u = AM1; A1u = AM1; m0A = m0 - Msplit; }

    // ---- staging lane decomposition (BK-generic) ----
    const int arow = lane / (BK / 8);           // row-in-chunk
    const int kg   = lane % (BK / 8);           // k-group in row
    const int key  = (BK == 64) ? (arow & 7) : ((arow >> 1) & 3);
    const int koff = (kg ^ key) * 8;            // swizzled k offset

    facc acc[4][NJ];
    #pragma unroll
    for (int i = 0; i < 4; ++i)
        #pragma unroll
        for (int j = 0; j < NJ; ++j)
            acc[i][j] = (facc){0.f, 0.f, 0.f, 0.f};

    auto stage = [&](int k0, ushort* buf) {
        ushort* Asb = buf;
        ushort* Bsb = buf + HBUF;
        #pragma unroll
        for (int t = 0; t < TC; ++t) {
            const int c = w * TC + t;
            gload16(BT + (size_t)(n0 + c * RPC + arow) * ldb + k0 + koff,
                    &Bsb[c * 512]);
        }
        if (k0 < KA2) {
            const ushort* Ab; int ko;
            if (k0 < KA1) { Ab = A0u; ko = k0; }
            else          { Ab = A1u; ko = k0 - KA1; }
            #pragma unroll
            for (int t = 0; t < TC; ++t) {
                const int c = w * TC + t;
                gload16(Ab + (size_t)(m0A + c * RPC + arow) * lda + ko + koff,
                        &Asb[c * 512]);
            }
        } else if (A2b) {  // bf16 third segment (direct to LDS)
            const int ko = k0 - KA2;
            #pragma unroll
            for (int t = 0; t < TC; ++t) {
                const int c = w * TC + t;
                gload16(A2b + (size_t)(m0A + c * RPC + arow) * ldaf + ko + koff,
                        &Asb[c * 512]);
            }
        } else {           // fp32 source: load + convert + ds_write
            const int ko = k0 - KA2;
            #pragma unroll
            for (int t = 0; t < TC; ++t) {
                const int c = w * TC + t;
                const float* src = A2f + (size_t)(m0A + c * RPC + arow) * ldaf + ko + koff;
                const float4 f0 = *(const float4*)src;
                const float4 f1 = *(const float4*)(src + 4);
                uint4 p;
                p.x = pack2(f0.x, f0.y); p.y = pack2(f0.z, f0.w);
                p.z = pack2(f1.x, f1.y); p.w = pack2(f1.z, f1.w);
                *(uint4*)&Asb[c * 512 + lane * 8] = p;
            }
        }
    };

    stage(0, sh);
    for (int k0 = 0; k0 < Ktot; k0 += BK) {
        ushort* cur = sh + (((k0 / BK) & 1)) * 2 * HBUF;
        ushort* nxt = sh + ((((k0 / BK) & 1)) ^ 1) * 2 * HBUF;
        __syncthreads();                       // drains stage(k0) (vmcnt+lgkm)
        if (k0 + BK < Ktot) stage(k0 + BK, nxt);   // overlaps compute below
        ushort* Asb = cur;
        ushort* Bsb = cur + HBUF;
        #pragma unroll
        for (int ks = 0; ks < BK / 32; ++ks) {
            const int ch = (BK == 64) ? ((ks * 4 + qd) ^ (ln & 7))
                                      : (qd ^ ((ln >> 1) & 3));
            bfrag af[4], bfv[NJ];
            #pragma unroll
            for (int i = 0; i < 4; ++i)
                af[i] = *(const bfrag*)&Asb[(wm + i*16 + ln) * BK + ch * 8];
            #pragma unroll
            for (int j = 0; j < NJ; ++j)
                bfv[j] = *(const bfrag*)&Bsb[(wn + j*16 + ln) * BK + ch * 8];
            #pragma unroll
            for (int i = 0; i < 4; ++i)
                #pragma unroll
                for (int j = 0; j < NJ; ++j)
                    acc[i][j] = __builtin_amdgcn_mfma_f32_16x16x32_bf16(
                        af[i], bfv[j], acc[i][j], 0, 0, 0);
        }
    }

    if constexpr (OMODE == 4) {
        const int seg   = n0 >> 10;        // 0=Q 1=K 2=V (block-uniform)
        const int nloc0 = n0 & 1023;
        const float* bs = (seg == 0) ? bias : (seg == 1) ? biasK : biasV;
        if (seg < 2) {
            ushort* ob = (seg == 0) ? outb : outbK;
            #pragma unroll
            for (int j = 0; j < NJ; ++j) {
                const int nl = nloc0 + wn + j * 16 + ln;
                const float bn = bs[nl];
                #pragma unroll
                for (int i = 0; i < 4; ++i) {
                    const int mb = m0 + wm + i * 16 + qd * 4;
                    #pragma unroll
                    for (int r = 0; r < 4; ++r) {
                        const float v = 1.f / (1.f + __expf(-(acc[i][j][r] + bn)));
                        const int m = mb + r;
                        const int g = m >> 9, l = m & 511;
                        ob[(((size_t)(g * NH + (nl >> 6))) * SL + l) * DH + (nl & 63)]
                            = f2bf(v);
                    }
                }
            }
        } else {
            // V: in-LDS swizzled transpose -> [g,h,d,l] coalesced stores
            // (uses 32 KB of sh -> fits both BK variants)
            __syncthreads();
            #pragma unroll
            for (int j = 0; j < NJ; ++j) {
                const int n_l = wn + j * 16 + ln;
                const float bn = bs[nloc0 + n_l];
                #pragma unroll
                for (int i = 0; i < 4; ++i) {
                    #pragma unroll
                    for (int r = 0; r < 4; ++r) {
                        const int m_l = wm + i * 16 + qd * 4 + r;
                        const int c = (m_l >> 3) ^ (n_l & 7);
                        sh[n_l * 128 + c * 8 + (m_l & 7)] = f2bf(acc[i][j][r] + bn);
                    }
                }
            }
            __syncthreads();
            const int n_l = tid >> 1, half = tid & 1;
            const int nl = nloc0 + n_l;
            const int g = m0 >> 9, l0 = m0 & 511;
            ushort* dst = outbVT +
                (((size_t)(g * NH + (nl >> 6))) * DH + (nl & 63)) * SL + l0;
            #pragma unroll
            for (int u = 0; u < 8; ++u) {
                const int c = half * 8 + u;
                const int cs = c ^ (n_l & 7);
                *(uint4*)(dst + c * 8) = *(const uint4*)&sh[n_l * 128 + cs * 8];
            }
        }
        return;
    } else {
        // ---- standard epilogue: C/D layout col=lane&15, row=qd*4+r ----
        #pragma unroll
        for (int j = 0; j < NJ; ++j) {
            const int n = n0 + wn + j * 16 + ln;
            const float bn = bias[n];
            #pragma unroll
            for (int i = 0; i < 4; ++i) {
                const int mb = m0 + wm + i * 16 + qd * 4;
                #pragma unroll
                for (int r = 0; r < 4; ++r) {
                    float v = acc[i][j][r] + bn;
                    if (ACT == 1)      v = 1.f / (1.f + __expf(-v));
                    else if (ACT == 2) v = v > 0.f ? v : 0.f;
                    const int m = mb + r;
                    if (OMODE == 0)      outf[(size_t)m * DM + n] = v;
                    else if (OMODE == 2) outb[(size_t)m * DM + n] = f2bf(v);
                    else {               // OMODE == 5: fp32 + bf16 side-copy
                        outf[(size_t)m * DM + n] = v;
                        if (m < Msplit) outb[(size_t)m * DM + n] = f2bf(v);
                    }
                }
            }
        }
    }
}

// ---------------------------------------------------------------------------
// Standalone GEMM kernel wrapper. BK=32 -> 32 KB LDS, min 4 waves/EU
// (4-5 blocks/CU); BK=64 -> 64 KB, min 2 waves/EU (2 blocks/CU).
// ---------------------------------------------------------------------------
template<int ACT, int OMODE, int WAVES, int BK>
__global__ __launch_bounds__(WAVES * 64, (BK == 32) ? 4 : 2)
void mfma_gemm(const ushort* __restrict__ A0, const ushort* __restrict__ A1,
               const float* __restrict__ A2f, const ushort* __restrict__ A2b,
               const int KA1, const int KA2, const int Ktot,
               const int lda, const int ldaf,
               const ushort* __restrict__ AM1, const int Msplit,
               const ushort* __restrict__ BT, const int ldb,
               const float* __restrict__ bias, const float* __restrict__ biasK,
               const float* __restrict__ biasV,
               float* __restrict__ outf, ushort* __restrict__ outb,
               ushort* __restrict__ outbK, ushort* __restrict__ outbVT,
               const int clustN)
{
    __shared__ char smem[BK * 1024];
    gemm_body<ACT, OMODE, WAVES, BK>(smem, blockIdx.x + gridDim.x * blockIdx.y,
                                     gridDim.x, gridDim.y,
                                     A0, A1, A2f, A2b, KA1, KA2, Ktot, lda, ldaf,
                                     AM1, Msplit, BT, ldb, bias, biasK, biasV,
                                     outf, outb, outbK, outbVT, clustN);
}

// ---------------------------------------------------------------------------
// MFMA fuzzy attention, both directions, 1D grid of 1024 blocks.
// (frozen at round-6 structure: swapped QK^T, packed b64 Es writes, in-lane
// partial row sums, XCD-pair K/V locality. See round-6 notes.)
// LDS = 16K (Ks) + 16K (VTs) + 32K (Es) = 64 KB -> 2 blocks/CU.
// ---------------------------------------------------------------------------
__global__ __launch_bounds__(256, 2)
void attn2m_k(const ushort* __restrict__ Qm, const ushort* __restrict__ Km,
              const ushort* __restrict__ VTm, ushort* __restrict__ AO0,
              ushort* __restrict__ AO1, float* __restrict__ RS0,
              float* __restrict__ RS1)
{
    __shared__ ushort Ks[128 * 64];
    __shared__ ushort VTs[64 * 128];
    __shared__ ushort Es[128 * 128];
    const int tid  = threadIdx.x;
    const int w    = tid >> 6;
    const int lane = tid & 63;
    const int ln   = lane & 15, qd = lane >> 4;
    const int wm  = (w & 1) * 64;          // q offset of this wave
    const int wns = (w >> 1) * 64;         // key offset (S stage)
    const int wnd = (w >> 1) * 32;         // d offset (PV stage)

    // ---- XCD-pair decode: qt fastest WITHIN an xcd ----
    const int L   = blockIdx.x;
    const int xcd = L & 7, s = L >> 3;     // s in [0,128)
    const int qt  = s & 3;
    const int pid = xcd * 32 + (s >> 2);   // pair id in [0,256)
    const int h   = pid & 15;
    const int zz  = pid >> 4;              // [0,16)
    const int dir = zz >> 3, b = zz & 7;

    const size_t HALFc = (size_t)NB * SL * DM;
    const ushort* Qall = Qm  + (dir ? HALFc : 0);
    const ushort* Kall = Km  + (dir ? 0 : HALFc);
    const ushort* Vall = VTm + (dir ? 0 : HALFc);
    ushort* AOp = dir ? AO1 : AO0;
    float*  RSp = dir ? RS1 : RS0;

    const size_t ho = ((size_t)(b * NH + h)) * SL * DH;
    const ushort* Qg  = Qall + ho + (size_t)qt * 128 * DH;
    const ushort* Kg  = Kall + ho;
    const ushort* VTg = Vall + ho;

    bfrag qf[4][2];
    #pragma unroll
    for (int i = 0; i < 4; ++i)
        #pragma unroll
        for (int ks = 0; ks < 2; ++ks)
            qf[i][ks] = *(const bfrag*)(Qg + (size_t)(wm + i*16 + ln) * DH + ks*32 + qd*8);

    facc oacc[4][2];
    #pragma unroll
    for (int i = 0; i < 4; ++i)
        #pragma unroll
        for (int j = 0; j < 2; ++j)
            oacc[i][j] = (facc){0.f, 0.f, 0.f, 0.f};
    float rp[4];   // per-lane partial row sums, q = wm + i*16 + ln
    #pragma unroll
    for (int i = 0; i < 4; ++i)
        rp[i] = 0.f;

    const int arow = lane >> 3;
    const int kc8s = ((lane & 7) ^ arow) * 8;
    const int vrow = lane >> 4;

    for (int kc = 0; kc < 4; ++kc) {
        __syncthreads();
        #pragma unroll
        for (int t = 0; t < 4; ++t) {
            const int c = w * 4 + t;
            const int vc8s = ((lane & 15) ^ ((c * 4 + vrow) & 7)) * 8;
            gload16(Kg + (size_t)(kc*128 + c*8 + arow) * DH + kc8s, &Ks[c * 512]);
            gload16(VTg + (size_t)(c*4 + vrow) * SL + kc*128 + vc8s, &VTs[c * 512]);
        }
        __syncthreads();

        // ---- swapped QK^T: sacc[j][i] = D[row=key][col=q] ----
        facc sacc[4][4];
        #pragma unroll
        for (int j = 0; j < 4; ++j)
            #pragma unroll
            for (int i = 0; i < 4; ++i)
                sacc[j][i] = (facc){0.f, 0.f, 0.f, 0.f};
        #pragma unroll
        for (int ks = 0; ks < 2; ++ks) {
            const int ch = (ks * 4 + qd) ^ (ln & 7);
            bfrag kf[4];
            #pragma unroll
            for (int j = 0; j < 4; ++j)
                kf[j] = *(const bfrag*)&Ks[(wns + j*16 + ln) * 64 + ch * 8];
            #pragma unroll
            for (int j = 0; j < 4; ++j)
                #pragma unroll
                for (int i = 0; i < 4; ++i)
                    sacc[j][i] = __builtin_amdgcn_mfma_f32_16x16x32_bf16(
                        kf[j], qf[i][ks], sacc[j][i], 0, 0, 0);
        }

        // ---- exp + packed Es write (b64) + in-lane partial row sum ----
        #pragma unroll
        for (int i = 0; i < 4; ++i) {
            const int q  = wm + i*16 + ln;
            const int qs = q & 7;
            float p = 0.f;
            #pragma unroll
            for (int j = 0; j < 4; ++j) {
                const int key0 = wns + j*16 + qd*4;   // 4 consecutive keys
                const float e0 = __expf(sacc[j][i][0] * 0.015625f);
                const float e1 = __expf(sacc[j][i][1] * 0.015625f);
                const float e2 = __expf(sacc[j][i][2] * 0.015625f);
                const float e3 = __expf(sacc[j][i][3] * 0.015625f);
                const int c = ((key0 & 127) >> 3) ^ qs;
                uint2 pk;
                pk.x = pack2(e0, e1);
                pk.y = pack2(e2, e3);
                *(uint2*)&Es[q * 128 + c * 8 + (key0 & 7)] = pk;
                p += (e0 + e1) + (e2 + e3);
            }
            rp[i] += p;
        }
        __syncthreads();

        // ---- PV (unchanged) ----
        #pragma unroll
        for (int ks2 = 0; ks2 < 4; ++ks2) {
            const int vch = (ks2 * 4 + qd) ^ (ln & 7);
            bfrag ea[4], vb[2];
            #pragma unroll
            for (int i = 0; i < 4; ++i) {
                const int q = wm + i*16 + ln;
                const int cs = (ks2*4 + qd) ^ (q & 7);
                ea[i] = *(const bfrag*)&Es[q * 128 + cs * 8];
            }
            #pragma unroll
            for (int j = 0; j < 2; ++j)
                vb[j] = *(const bfrag*)&VTs[(wnd + j*16 + ln) * 128 + vch * 8];
            #pragma unroll
            for (int i = 0; i < 4; ++i)
                #pragma unroll
                for (int j = 0; j < 2; ++j)
                    oacc[i][j] = __builtin_amdgcn_mfma_f32_16x16x32_bf16(
                        ea[i], vb[j], oacc[i][j], 0, 0, 0);
        }
    }

    // ---- deferred reduction across qd groups (lanes ln+16k share q) ----
    #pragma unroll
    for (int i = 0; i < 4; ++i) {
        float p = rp[i];
        p += __shfl_xor(p, 16);
        p += __shfl_xor(p, 32);
        rp[i] = p;
    }

    __syncthreads();
    float* rsls = (float*)Ks;
    if (qd == 0) {
        #pragma unroll
        for (int i = 0; i < 4; ++i)
            rsls[(w >> 1) * 128 + wm + i*16 + ln] = rp[i];
    }
    __syncthreads();
    if (tid < 128) {
        const float t = rsls[tid] + rsls[128 + tid];
        RSp[(size_t)(b * NH + h) * SL + qt * 128 + tid] = t;
        rsls[tid] = t;
    }
    __syncthreads();

    #pragma unroll
    for (int i = 0; i < 4; ++i) {
        #pragma unroll
        for (int r = 0; r < 4; ++r) {
            const int q = wm + i*16 + qd*4 + r;
            const float inv = 1.f / rsls[q];
            const size_t rowo = ((size_t)(b*SL + qt*128 + q)) * DM + h*DH;
            #pragma unroll
            for (int j = 0; j < 2; ++j)
                AOp[rowo + wnd + j*16 + ln] = f2bf(oacc[i][j][r] * inv);
        }
    }
}

// ---------------------------------------------------------------------------
// avg_attn body: one 64x64 avga tile, 16-head loop (round-0 structure).
// Caller provides >= 16640 B of LDS.
// ---------------------------------------------------------------------------
__device__ __forceinline__ void avg3_body(void* smem_, const int kt,
                                          const int qt, const int b,
                                          const ushort* __restrict__ Qm,
                                          const ushort* __restrict__ Km,
                                          const float* __restrict__ RS,
                                          float* __restrict__ avga)
{
    ushort* Qs = (ushort*)smem_;          // 64*64
    ushort* Kt = Qs + 64 * 64;            // 64*64
    float* rss = (float*)(Kt + 64 * 64);  // 64
    const int tid  = threadIdx.x;
    const int w    = tid >> 6;
    const int lane = tid & 63;
    const int ln   = lane & 15, qd = lane >> 4;
    const int wq = (w & 1) * 32, wk = (w >> 1) * 32;

    const int arow = lane >> 3;
    const int kc8s = ((lane & 7) ^ arow) * 8;

    float acc[2][2][4];
    #pragma unroll
    for (int i = 0; i < 2; ++i)
        #pragma unroll
        for (int j = 0; j < 2; ++j)
            #pragma unroll
            for (int r = 0; r < 4; ++r)
                acc[i][j][r] = 0.f;

    for (int h = 0; h < NH; ++h) {
        const size_t ho = ((size_t)(b * NH + h)) * SL * DH;
        __syncthreads();
        #pragma unroll
        for (int t = 0; t < 2; ++t) {
            const int c = w * 2 + t;
            gload16(Qm + ho + (size_t)(qt*64 + c*8 + arow) * DH + kc8s, &Qs[c * 512]);
            gload16(Km + ho + (size_t)(kt*64 + c*8 + arow) * DH + kc8s, &Kt[c * 512]);
        }
        if (tid < 64) rss[tid] = RS[(size_t)(b*NH + h)*SL + qt*64 + tid];
        __syncthreads();

        facc s[2][2];
        #pragma unroll
        for (int i = 0; i < 2; ++i)
            #pragma unroll
            for (int j = 0; j < 2; ++j)
                s[i][j] = (facc){0.f, 0.f, 0.f, 0.f};
        #pragma unroll
        for (int ks = 0; ks < 2; ++ks) {
            const int ch = (ks * 4 + qd) ^ (ln & 7);
            bfrag qa[2], kb[2];
            #pragma unroll
            for (int i = 0; i < 2; ++i)
                qa[i] = *(const bfrag*)&Qs[(wq + i*16 + ln) * 64 + ch * 8];
            #pragma unroll
            for (int j = 0; j < 2; ++j)
                kb[j] = *(const bfrag*)&Kt[(wk + j*16 + ln) * 64 + ch * 8];
            #pragma unroll
            for (int i = 0; i < 2; ++i)
                #pragma unroll
                for (int j = 0; j < 2; ++j)
                    s[i][j] = __builtin_amdgcn_mfma_f32_16x16x32_bf16(
                        qa[i], kb[j], s[i][j], 0, 0, 0);
        }
        #pragma unroll
        for (int i = 0; i < 2; ++i) {
            #pragma unroll
            for (int r = 0; r < 4; ++r) {
                const float ir = 0.0625f / rss[wq + i*16 + qd*4 + r];
                #pragma unroll
                for (int j = 0; j < 2; ++j)
                    acc[i][j][r] += __expf(s[i][j][r] * 0.015625f) * ir;
            }
        }
    }
    #pragma unroll
    for (int i = 0; i < 2; ++i) {
        #pragma unroll
        for (int r = 0; r < 4; ++r) {
            const int q = wq + i*16 + qd*4 + r;
            #pragma unroll
            for (int j = 0; j < 2; ++j)
                avga[((size_t)(b*SL + qt*64 + q)) * SL + kt*64 + wk + j*16 + ln]
                    = acc[i][j][r];
        }
    }
}

// ---------------------------------------------------------------------------
// mid_k: interleave the two INDEPENDENT post-attention jobs so each CU
// co-hosts MFMA-bound Wo-GEMM blocks and latency-bound avg3 blocks.
// Even blocks = Wo-GEMM tile (BK=32 -> 32 KB smem -> 4 blocks/CU; the
// 1024-block grid now fits ONE scheduling round), odd = avg3 tile.
// Disjointness: avg3 reads Qb[first half], Kb[second half], RS; Wo reads
// AOt/AOi/WoT, writes out rows + bf16 side-copy to Kb[first half].
// ---------------------------------------------------------------------------
__global__ __launch_bounds__(256, 4)
void mid_k(const ushort* __restrict__ AOt, const ushort* __restrict__ AOi,
           const ushort* __restrict__ WoT, const float* __restrict__ bo,
           float* __restrict__ text_cross, ushort* __restrict__ tcb,
           const ushort* __restrict__ Qm, const ushort* __restrict__ Km,
           const float* __restrict__ RS, float* __restrict__ avga)
{
    __shared__ char smem[32768];
    const int bid = blockIdx.x;
    if (bid & 1) {
        const int la = bid >> 1;           // [0,512): kt fastest, then qt, b
        avg3_body(smem, la & 7, (la >> 3) & 7, la >> 6, Qm, Km, RS, avga);
    } else {
        gemm_body<0, 5, 4, 32>(smem, bid >> 1, 8, 64,
            AOt, AOt, nullptr, nullptr, DM, DM, DM, DM, DM,
            AOi, 4096, WoT, DM, bo, nullptr, nullptr,
            text_cross, tcb, nullptr, nullptr, 0);
    }
}

// ---------------------------------------------------------------------------
extern "C" void kernel_launch(void* const* d_in, const int* in_sizes, int n_in,
                              void* d_out, int out_size, void* d_ws, size_t ws_size,
                              hipStream_t stream)
{
    (void)in_sizes; (void)n_in; (void)out_size;
    const float* text  = (const float*)d_in[0];
    const float* image = (const float*)d_in[1];
    const float* Wq = (const float*)d_in[2];
    const float* bq = (const float*)d_in[3];
    const float* Wk = (const float*)d_in[4];
    const float* bk = (const float*)d_in[5];
    const float* Wv = (const float*)d_in[6];
    const float* bv = (const float*)d_in[7];
    const float* Wo = (const float*)d_in[8];
    const float* bo = (const float*)d_in[9];
    const float* W1 = (const float*)d_in[10];
    const float* b1 = (const float*)d_in[11];
    const float* W2 = (const float*)d_in[12];
    const float* b2 = (const float*)d_in[13];
    float* out = (float*)d_out;

    const size_t SZ   = (size_t)NB * SL * DM;   // 4,194,304
    const size_t HALF = SZ;

    // ---- fixed workspace layout (bf16 = ushort), ~82.1 MB ----
    ushort* xbf = (ushort*)d_ws;        // [8192,1024] text 0..4095, image 4096..
    ushort* Qb  = xbf + 2*SZ;           // [16,NH,SL,DH]
    ushort* Kb  = Qb  + 2*SZ;           // [16,NH,SL,DH]; later bf16 text_cross
    ushort* VT  = Kb  + 2*SZ;           // [16,NH,DH,SL]
    ushort* AOt = VT  + 2*SZ;           // [4096,1024]
    ushort* Wt  = AOt + SZ;             // Wq^T|Wk^T|Wv^T, later W1^T (fallback)
    float*  RS  = (float*)(Wt + 3*DM*DM);   // [8,NH,SL]
    char*   wsEnd = (char*)(RS + NB*NH*SL);
    ushort* hidden = Qb;                // reuses Q (dead after mid_k)

    float* text_cross = out;            // Wo gemm writes rows 0..8191 (both)
    float* comp       = out + 2*SZ;
    float* avga       = out + 3*SZ;

    // ---- scratch tiers ----
    // tier A (round-7 proven): RS2, WoT, AOi, W2T in ws
    // tier B (round-8 proven): + W1T slot -> W1/W2 transposes fold into prep_k
    const size_t extA = (size_t)NB*NH*SL*4 + (size_t)DM*DM*2
                      + (size_t)SZ*2 + (size_t)DM*DM*2;
    const size_t extB = extA + (size_t)3*DM*DM*2;
    const size_t fixBytes = (size_t)(wsEnd - (char*)d_ws);
    float* RS2; ushort* WoT; ushort* AOi; ushort* W2T; ushort* W1Tx;
    const bool haveA = (ws_size >= fixBytes + extA);
    const bool haveB = (ws_size >= fixBytes + extB);
    if (haveA) {
        RS2 = (float*)wsEnd;
        WoT = (ushort*)(RS2 + NB*NH*SL);
        AOi = WoT + DM*DM;
        W2T = AOi + SZ;
        W1Tx = haveB ? (W2T + DM*DM) : Wt;
    } else {                            // fallback (correctness-first)
        WoT = (ushort*)comp;
        AOi = WoT + DM*DM;
        RS2 = (float*)Wt;
        W2T = AOt;                      // dead after Wo gemm (inside mid_k)
        W1Tx = Wt;
    }

    const dim3 blk(256);

    // ---- prep: cvt + Wq/Wk/Wv/Wo transposes [+ W1/W2 when tier B] ----
    prep_k<<<haveB ? 10240 : 9216, blk, 0, stream>>>(
        text, image, Wq, Wk, Wv, Wo, W1, W2, xbf, Wt, WoT, W1Tx, W2T);

    // ---- fused Q/K/V projection: M=8192, N=3072 (BK=32: 4-5 blocks/CU) ----
    mfma_gemm<0,4,4,32><<<dim3(24,64), blk, 0, stream>>>(
        xbf, xbf, nullptr, nullptr, DM, DM, DM, DM, DM, nullptr, 0,
        Wt, DM, bq, bk, bv, nullptr, Qb, Kb, VT, 1);

    // ---- both attention directions (1D grid, XCD-pair swizzle) ----
    attn2m_k<<<dim3(1024), blk, 0, stream>>>(Qb, Kb, VT, AOt, AOi, RS, RS2);

    // ---- mid: avg3 (odd) interleaved with Wo gemm (even), 4 blocks/CU ----
    mid_k<<<1024, blk, 0, stream>>>(AOt, AOi, WoT, bo, text_cross, Kb,
                                    Qb, Kb + HALF, RS, avga);
    if (!haveB)   // W1/W2 transposes not folded into prep
        tconvW12_k<<<1024, blk, 0, stream>>>(W1, W2, W1Tx, W2T);

    // ---- MLP (8-wave BK=64 GEMMs: proven round-8 config) ----
    mfma_gemm<2,2,8,64><<<dim3(8,32), dim3(512), 0, stream>>>(
        xbf, xbf + SZ, nullptr, Kb, DM, 2*DM, 3*DM, DM, DM, nullptr, 0,
        W1Tx, 3*DM, b1, nullptr, nullptr, nullptr, hidden, nullptr, nullptr, 0);
    mfma_gemm<0,0,8,64><<<dim3(8,32), dim3(512), 0, stream>>>(
        hidden, hidden, nullptr, nullptr, DM, DM, DM, DM, DM, nullptr, 0,
        W2T, DM, b2, nullptr, nullptr, comp, nullptr, nullptr, nullptr, 0);
}

// Round 10
// 333.827 us; speedup vs baseline: 1.0062x; 1.0062x over previous
//
#include <hip/hip_runtime.h>

#define NB 8
#define SL 512
#define DM 1024
#define NH 16
#define DH 64

using bfrag = __attribute__((ext_vector_type(8))) short;   // 8 bf16 (4 VGPRs)
using facc  = __attribute__((ext_vector_type(4))) float;   // 4 fp32 acc

__device__ __forceinline__ float bf2f(ushort u) {
    return __uint_as_float(((unsigned)u) << 16);
}
__device__ __forceinline__ ushort f2bf(float f) {
    unsigned x = __float_as_uint(f);
    return (ushort)((x + 0x7FFFu + ((x >> 16) & 1u)) >> 16);   // RNE
}
__device__ __forceinline__ unsigned pack2(float a, float b) {
    return (unsigned)f2bf(a) | ((unsigned)f2bf(b) << 16);
}
__device__ __forceinline__ void gload16(const ushort* g, ushort* l) {
    __builtin_amdgcn_global_load_lds(
        (const __attribute__((address_space(1))) unsigned*)g,
        (__attribute__((address_space(3))) unsigned*)l, 16, 0, 0);
}

// ---------------------------------------------------------------------------
// Transpose-convert body: W[R,C] fp32 -> WT[C,R] bf16, one 64x64 tile.
// Caller provides >= 8704 B of LDS.
// ---------------------------------------------------------------------------
__device__ __forceinline__ void tconv_body(void* smem_,
                                           const float* __restrict__ W,
                                           ushort* __restrict__ WT,
                                           const int R, const int C,
                                           const int c0, const int r0) {
    ushort (*T)[68] = (ushort (*)[68])smem_;
    const int tid = threadIdx.x;
    #pragma unroll
    for (int rr = 0; rr < 4; ++rr) {
        const int r = (tid >> 4) + rr * 16;
        const int c4 = (tid & 15) * 4;
        const float4 f = *(const float4*)(W + (size_t)(r0 + r) * C + c0 + c4);
        T[c4+0][r] = f2bf(f.x); T[c4+1][r] = f2bf(f.y);
        T[c4+2][r] = f2bf(f.z); T[c4+3][r] = f2bf(f.w);
    }
    __syncthreads();
    #pragma unroll
    for (int rr = 0; rr < 4; ++rr) {
        const int c = (tid >> 4) + rr * 16;
        const int r4 = (tid & 15) * 4;
        *(ushort4*)(WT + (size_t)(c0 + c) * R + r0 + r4) =
            make_ushort4(T[c][r4+0], T[c][r4+1], T[c][r4+2], T[c][r4+3]);
    }
}

// ---------------------------------------------------------------------------
// prep: cvt text+image (0..8191) + transpose Wq/Wk/Wv/Wo (8192..9215)
// [+ W1/W2 (9216..10239) when launched with the extended grid].
// ---------------------------------------------------------------------------
__global__ __launch_bounds__(256)
void prep_k(const float* __restrict__ text, const float* __restrict__ image,
            const float* __restrict__ Wq, const float* __restrict__ Wk,
            const float* __restrict__ Wv, const float* __restrict__ Wo,
            const float* __restrict__ W1, const float* __restrict__ W2,
            ushort* __restrict__ xbf, ushort* __restrict__ Wt,
            ushort* __restrict__ WoT, ushort* __restrict__ W1T,
            ushort* __restrict__ W2T)
{
    __shared__ ushort Tbuf[64][68];
    const int bid = blockIdx.x;
    const size_t SZc = (size_t)NB * SL * DM;
    if (bid < 8192) {
        const int half = bid >> 12;
        const float* s = half ? image : text;
        ushort* d = xbf + (size_t)half * SZc;
        const size_t i = ((size_t)(bid & 4095) * 256 + threadIdx.x) * 4;
        const float4 f = *(const float4*)(s + i);
        *(ushort4*)(d + i) =
            make_ushort4(f2bf(f.x), f2bf(f.y), f2bf(f.z), f2bf(f.w));
    } else if (bid < 9216) {
        const int t = bid - 8192;
        const int wsel = t >> 8, tt = t & 255;
        const float* W = (wsel == 0) ? Wq : (wsel == 1) ? Wk
                       : (wsel == 2) ? Wv : Wo;
        ushort* WT = (wsel < 3) ? Wt + (size_t)wsel * DM * DM : WoT;
        tconv_body(Tbuf, W, WT, DM, DM, (tt & 15) * 64, (tt >> 4) * 64);
    } else {
        const int t = bid - 9216;
        if (t < 768)
            tconv_body(Tbuf, W1, W1T, 3 * DM, DM, (t & 15) * 64, (t >> 4) * 64);
        else {
            const int u = t - 768;
            tconv_body(Tbuf, W2, W2T, DM, DM, (u & 15) * 64, (u >> 4) * 64);
        }
    }
}

// ---------------------------------------------------------------------------
// W1 [3072,1024] (blocks 0..767) + W2 [1024,1024] (768..1023) transposes.
// (fallback path only; extended path folds these into prep_k)
// ---------------------------------------------------------------------------
__global__ __launch_bounds__(256)
void tconvW12_k(const float* __restrict__ W1, const float* __restrict__ W2,
                ushort* __restrict__ W1T, ushort* __restrict__ W2T)
{
    __shared__ ushort Tbuf[64][68];
    const int bid = blockIdx.x;
    if (bid < 768)
        tconv_body(Tbuf, W1, W1T, 3 * DM, DM, (bid & 15) * 64, (bid >> 4) * 64);
    else {
        const int t = bid - 768;
        tconv_body(Tbuf, W2, W2T, DM, DM, (t & 15) * 64, (t >> 4) * 64);
    }
}

// ---------------------------------------------------------------------------
// bf16 MFMA GEMM body: 128x128 tile, WAVES in {4,8}, BK=64, double-buffered
// LDS staging (one barrier per K-iter; stage(k+1) overlaps compute(k)).
// WAVES=4: 2x2 waves of 64x64 (acc 4x4), 256 thr -> 2 waves/SIMD at
//   2 blocks/CU. WAVES=8: 2x4 waves of 64x32 (acc 4x2), 512 thr ->
//   4 waves/SIMD at 2 blocks/CU (or 2/SIMD at 1 block/CU for the MLP
//   grids) — double the latency-hiding pool inside the SAME barrier
//   structure. (Round-9 lesson: BK=32 doubled barrier count and lost;
//   wave-count is the lever, not barrier granularity.)
//   out[m,n] = ACT( sum_k A[m,k]*B[k,n] + bias[n] ),  B given as BT[n,k].
// A K-concat: A0 | A1 (bf16) | third segment = A2b (bf16) if non-null else
// A2f (fp32 load+convert). M-concat: rows >= Msplit from AM1 (block-uniform).
// XCD swizzle on logical index L. OMODE 0: fp32 row-major. 2: bf16.
// 4: fused QKV epilogue. 5: fp32 + bf16 side-copy.
// Caller provides 64 KB LDS.
// ---------------------------------------------------------------------------
template<int ACT, int OMODE, int WAVES>
__device__ __forceinline__ void gemm_body(
    void* smem_, const int L, const int NTg, const int MTg,
    const ushort* __restrict__ A0, const ushort* __restrict__ A1,
    const float* __restrict__ A2f, const ushort* __restrict__ A2b,
    const int KA1, const int KA2, const int Ktot,
    const int lda, const int ldaf,
    const ushort* __restrict__ AM1, const int Msplit,
    const ushort* __restrict__ BT, const int ldb,
    const float* __restrict__ bias, const float* __restrict__ biasK,
    const float* __restrict__ biasV,
    float* __restrict__ outf, ushort* __restrict__ outb,
    ushort* __restrict__ outbK, ushort* __restrict__ outbVT,
    const int clustN)
{
    constexpr int NJ = (WAVES == 4) ? 4 : 2;   // n-frags per wave
    constexpr int TC = 16 / WAVES;             // stage chunk iters per wave
    ushort* sh = (ushort*)smem_;   // 2 buffers x (As 8192 + Bs 8192), 64 KB
    const int tid  = threadIdx.x;
    const int w    = tid >> 6;
    const int lane = tid & 63;
    const int ln   = lane & 15, qd = lane >> 4;
    const int wm = (w & 1) * 64;
    const int wn = (WAVES == 4) ? (w >> 1) * 64 : (w >> 1) * 32;

    // ---- XCD-clustered block swizzle ----
    const int xcd = L & 7, sIdx = L >> 3;
    int mt, nt;
    if (clustN) { const int np = NTg >> 3; nt = xcd * np + sIdx % np; mt = sIdx / np; }
    else        { mt = xcd * (MTg >> 3) + sIdx / NTg; nt = sIdx - (sIdx / NTg) * NTg; }
    const int m0 = mt * 128, n0 = nt * 128;

    // ---- M-concat source select (block-uniform) ----
    const ushort* A0u = A0; const ushort* A1u = A1; int m0A = m0;
    if (Msplit && m0 >= Msplit) { A0u = AM1; A1u = AM1; m0A = m0 - Msplit; }

    const int arow = (lane >> 3);               // row-in-chunk 0..7
    const int kc8s = ((lane & 7) ^ arow) * 8;   // swizzled global k-chunk

    facc acc[4][NJ];
    #pragma unroll
    for (int i = 0; i < 4; ++i)
        #pragma unroll
        for (int j = 0; j < NJ; ++j)
            acc[i][j] = (facc){0.f, 0.f, 0.f, 0.f};

    auto stage = [&](int k0, ushort* buf) {
        ushort* Asb = buf;
        ushort* Bsb = buf + 8192;
        #pragma unroll
        for (int t = 0; t < TC; ++t) {
            const int c = w * TC + t;
            gload16(BT + (size_t)(n0 + c * 8 + arow) * ldb + k0 + kc8s,
                    &Bsb[c * 512]);
        }
        if (k0 < KA2) {
            const ushort* Ab; int ko;
            if (k0 < KA1) { Ab = A0u; ko = k0; }
            else          { Ab = A1u; ko = k0 - KA1; }
            #pragma unroll
            for (int t = 0; t < TC; ++t) {
                const int c = w * TC + t;
                gload16(Ab + (size_t)(m0A + c * 8 + arow) * lda + ko + kc8s,
                        &Asb[c * 512]);
            }
        } else if (A2b) {  // bf16 third segment (direct to LDS)
            const int ko = k0 - KA2;
            #pragma unroll
            for (int t = 0; t < TC; ++t) {
                const int c = w * TC + t;
                gload16(A2b + (size_t)(m0A + c * 8 + arow) * ldaf + ko + kc8s,
                        &Asb[c * 512]);
            }
        } else {           // fp32 source: load + convert + ds_write
            const int ko = k0 - KA2;
            #pragma unroll
            for (int t = 0; t < TC; ++t) {
                const int c = w * TC + t;
                const float* src = A2f + (size_t)(m0A + c * 8 + arow) * ldaf + ko + kc8s;
                const float4 f0 = *(const float4*)src;
                const float4 f1 = *(const float4*)(src + 4);
                uint4 p;
                p.x = pack2(f0.x, f0.y); p.y = pack2(f0.z, f0.w);
                p.z = pack2(f1.x, f1.y); p.w = pack2(f1.z, f1.w);
                *(uint4*)&Asb[c * 512 + lane * 8] = p;
            }
        }
    };

    stage(0, sh);
    for (int k0 = 0; k0 < Ktot; k0 += 64) {
        ushort* cur = sh + ((k0 >> 6) & 1) * 16384;
        ushort* nxt = sh + (((k0 >> 6) & 1) ^ 1) * 16384;
        __syncthreads();                       // drains stage(k0) (vmcnt+lgkm)
        if (k0 + 64 < Ktot) stage(k0 + 64, nxt);   // overlaps compute below
        ushort* Asb = cur;
        ushort* Bsb = cur + 8192;
        #pragma unroll
        for (int ks = 0; ks < 2; ++ks) {
            const int ch = (ks * 4 + qd) ^ (ln & 7);   // swizzled chunk
            bfrag af[4], bfv[NJ];
            #pragma unroll
            for (int i = 0; i < 4; ++i)
                af[i] = *(const bfrag*)&Asb[(wm + i*16 + ln) * 64 + ch * 8];
            #pragma unroll
            for (int j = 0; j < NJ; ++j)
                bfv[j] = *(const bfrag*)&Bsb[(wn + j*16 + ln) * 64 + ch * 8];
            #pragma unroll
            for (int i = 0; i < 4; ++i)
                #pragma unroll
                for (int j = 0; j < NJ; ++j)
                    acc[i][j] = __builtin_amdgcn_mfma_f32_16x16x32_bf16(
                        af[i], bfv[j], acc[i][j], 0, 0, 0);
        }
    }

    if constexpr (OMODE == 4) {
        const int seg   = n0 >> 10;        // 0=Q 1=K 2=V (block-uniform)
        const int nloc0 = n0 & 1023;
        const float* bs = (seg == 0) ? bias : (seg == 1) ? biasK : biasV;
        if (seg < 2) {
            ushort* ob = (seg == 0) ? outb : outbK;
            #pragma unroll
            for (int j = 0; j < NJ; ++j) {
                const int nl = nloc0 + wn + j * 16 + ln;
                const float bn = bs[nl];
                #pragma unroll
                for (int i = 0; i < 4; ++i) {
                    const int mb = m0 + wm + i * 16 + qd * 4;
                    #pragma unroll
                    for (int r = 0; r < 4; ++r) {
                        const float v = 1.f / (1.f + __expf(-(acc[i][j][r] + bn)));
                        const int m = mb + r;
                        const int g = m >> 9, l = m & 511;
                        ob[(((size_t)(g * NH + (nl >> 6))) * SL + l) * DH + (nl & 63)]
                            = f2bf(v);
                    }
                }
            }
        } else {
            // V: in-LDS swizzled transpose -> [g,h,d,l] coalesced stores
            __syncthreads();
            #pragma unroll
            for (int j = 0; j < NJ; ++j) {
                const int n_l = wn + j * 16 + ln;
                const float bn = bs[nloc0 + n_l];
                #pragma unroll
                for (int i = 0; i < 4; ++i) {
                    #pragma unroll
                    for (int r = 0; r < 4; ++r) {
                        const int m_l = wm + i * 16 + qd * 4 + r;
                        const int c = (m_l >> 3) ^ (n_l & 7);
                        sh[n_l * 128 + c * 8 + (m_l & 7)] = f2bf(acc[i][j][r] + bn);
                    }
                }
            }
            __syncthreads();
            // WAVES-generic copy-out: TPN threads per n_l row, 16/TPN
            // 16B-chunks each (TPN=2 reproduces the proven 4-wave path).
            constexpr int TPN = (WAVES * 64) / 128;
            constexpr int CPT = 16 / TPN;
            const int n_l = tid / TPN, sub = tid % TPN;
            const int nl = nloc0 + n_l;
            const int g = m0 >> 9, l0 = m0 & 511;
            ushort* dst = outbVT +
                (((size_t)(g * NH + (nl >> 6))) * DH + (nl & 63)) * SL + l0;
            #pragma unroll
            for (int u = 0; u < CPT; ++u) {
                const int c = sub * CPT + u;
                const int cs = c ^ (n_l & 7);
                *(uint4*)(dst + c * 8) = *(const uint4*)&sh[n_l * 128 + cs * 8];
            }
        }
        return;
    } else {
        // ---- standard epilogue: C/D layout col=lane&15, row=qd*4+r ----
        #pragma unroll
        for (int j = 0; j < NJ; ++j) {
            const int n = n0 + wn + j * 16 + ln;
            const float bn = bias[n];
            #pragma unroll
            for (int i = 0; i < 4; ++i) {
                const int mb = m0 + wm + i * 16 + qd * 4;
                #pragma unroll
                for (int r = 0; r < 4; ++r) {
                    float v = acc[i][j][r] + bn;
                    if (ACT == 1)      v = 1.f / (1.f + __expf(-v));
                    else if (ACT == 2) v = v > 0.f ? v : 0.f;
                    const int m = mb + r;
                    if (OMODE == 0)      outf[(size_t)m * DM + n] = v;
                    else if (OMODE == 2) outb[(size_t)m * DM + n] = f2bf(v);
                    else {               // OMODE == 5: fp32 + bf16 side-copy
                        outf[(size_t)m * DM + n] = v;
                        if (m < Msplit) outb[(size_t)m * DM + n] = f2bf(v);
                    }
                }
            }
        }
    }
}

// ---------------------------------------------------------------------------
// Standalone GEMM kernel wrapper.
// ---------------------------------------------------------------------------
template<int ACT, int OMODE, int WAVES>
__global__ __launch_bounds__(WAVES * 64, 2)
void mfma_gemm(const ushort* __restrict__ A0, const ushort* __restrict__ A1,
               const float* __restrict__ A2f, const ushort* __restrict__ A2b,
               const int KA1, const int KA2, const int Ktot,
               const int lda, const int ldaf,
               const ushort* __restrict__ AM1, const int Msplit,
               const ushort* __restrict__ BT, const int ldb,
               const float* __restrict__ bias, const float* __restrict__ biasK,
               const float* __restrict__ biasV,
               float* __restrict__ outf, ushort* __restrict__ outb,
               ushort* __restrict__ outbK, ushort* __restrict__ outbVT,
               const int clustN)
{
    __shared__ char smem[65536];
    gemm_body<ACT, OMODE, WAVES>(smem, blockIdx.x + gridDim.x * blockIdx.y,
                                 gridDim.x, gridDim.y,
                                 A0, A1, A2f, A2b, KA1, KA2, Ktot, lda, ldaf,
                                 AM1, Msplit, BT, ldb, bias, biasK, biasV,
                                 outf, outb, outbK, outbVT, clustN);
}

// ---------------------------------------------------------------------------
// MFMA fuzzy attention, both directions, 1D grid of 1024 blocks.
// (frozen at round-6 structure: swapped QK^T, packed b64 Es writes, in-lane
// partial row sums, XCD-pair K/V locality. See round-6 notes.)
// LDS = 16K (Ks) + 16K (VTs) + 32K (Es) = 64 KB -> 2 blocks/CU.
// ---------------------------------------------------------------------------
__global__ __launch_bounds__(256, 2)
void attn2m_k(const ushort* __restrict__ Qm, const ushort* __restrict__ Km,
              const ushort* __restrict__ VTm, ushort* __restrict__ AO0,
              ushort* __restrict__ AO1, float* __restrict__ RS0,
              float* __restrict__ RS1)
{
    __shared__ ushort Ks[128 * 64];
    __shared__ ushort VTs[64 * 128];
    __shared__ ushort Es[128 * 128];
    const int tid  = threadIdx.x;
    const int w    = tid >> 6;
    const int lane = tid & 63;
    const int ln   = lane & 15, qd = lane >> 4;
    const int wm  = (w & 1) * 64;          // q offset of this wave
    const int wns = (w >> 1) * 64;         // key offset (S stage)
    const int wnd = (w >> 1) * 32;         // d offset (PV stage)

    // ---- XCD-pair decode: qt fastest WITHIN an xcd ----
    const int L   = blockIdx.x;
    const int xcd = L & 7, s = L >> 3;     // s in [0,128)
    const int qt  = s & 3;
    const int pid = xcd * 32 + (s >> 2);   // pair id in [0,256)
    const int h   = pid & 15;
    const int zz  = pid >> 4;              // [0,16)
    const int dir = zz >> 3, b = zz & 7;

    const size_t HALFc = (size_t)NB * SL * DM;
    const ushort* Qall = Qm  + (dir ? HALFc : 0);
    const ushort* Kall = Km  + (dir ? 0 : HALFc);
    const ushort* Vall = VTm + (dir ? 0 : HALFc);
    ushort* AOp = dir ? AO1 : AO0;
    float*  RSp = dir ? RS1 : RS0;

    const size_t ho = ((size_t)(b * NH + h)) * SL * DH;
    const ushort* Qg  = Qall + ho + (size_t)qt * 128 * DH;
    const ushort* Kg  = Kall + ho;
    const ushort* VTg = Vall + ho;

    bfrag qf[4][2];
    #pragma unroll
    for (int i = 0; i < 4; ++i)
        #pragma unroll
        for (int ks = 0; ks < 2; ++ks)
            qf[i][ks] = *(const bfrag*)(Qg + (size_t)(wm + i*16 + ln) * DH + ks*32 + qd*8);

    facc oacc[4][2];
    #pragma unroll
    for (int i = 0; i < 4; ++i)
        #pragma unroll
        for (int j = 0; j < 2; ++j)
            oacc[i][j] = (facc){0.f, 0.f, 0.f, 0.f};
    float rp[4];   // per-lane partial row sums, q = wm + i*16 + ln
    #pragma unroll
    for (int i = 0; i < 4; ++i)
        rp[i] = 0.f;

    const int arow = lane >> 3;
    const int kc8s = ((lane & 7) ^ arow) * 8;
    const int vrow = lane >> 4;

    for (int kc = 0; kc < 4; ++kc) {
        __syncthreads();
        #pragma unroll
        for (int t = 0; t < 4; ++t) {
            const int c = w * 4 + t;
            const int vc8s = ((lane & 15) ^ ((c * 4 + vrow) & 7)) * 8;
            gload16(Kg + (size_t)(kc*128 + c*8 + arow) * DH + kc8s, &Ks[c * 512]);
            gload16(VTg + (size_t)(c*4 + vrow) * SL + kc*128 + vc8s, &VTs[c * 512]);
        }
        __syncthreads();

        // ---- swapped QK^T: sacc[j][i] = D[row=key][col=q] ----
        facc sacc[4][4];
        #pragma unroll
        for (int j = 0; j < 4; ++j)
            #pragma unroll
            for (int i = 0; i < 4; ++i)
                sacc[j][i] = (facc){0.f, 0.f, 0.f, 0.f};
        #pragma unroll
        for (int ks = 0; ks < 2; ++ks) {
            const int ch = (ks * 4 + qd) ^ (ln & 7);
            bfrag kf[4];
            #pragma unroll
            for (int j = 0; j < 4; ++j)
                kf[j] = *(const bfrag*)&Ks[(wns + j*16 + ln) * 64 + ch * 8];
            #pragma unroll
            for (int j = 0; j < 4; ++j)
                #pragma unroll
                for (int i = 0; i < 4; ++i)
                    sacc[j][i] = __builtin_amdgcn_mfma_f32_16x16x32_bf16(
                        kf[j], qf[i][ks], sacc[j][i], 0, 0, 0);
        }

        // ---- exp + packed Es write (b64) + in-lane partial row sum ----
        #pragma unroll
        for (int i = 0; i < 4; ++i) {
            const int q  = wm + i*16 + ln;
            const int qs = q & 7;
            float p = 0.f;
            #pragma unroll
            for (int j = 0; j < 4; ++j) {
                const int key0 = wns + j*16 + qd*4;   // 4 consecutive keys
                const float e0 = __expf(sacc[j][i][0] * 0.015625f);
                const float e1 = __expf(sacc[j][i][1] * 0.015625f);
                const float e2 = __expf(sacc[j][i][2] * 0.015625f);
                const float e3 = __expf(sacc[j][i][3] * 0.015625f);
                const int c = ((key0 & 127) >> 3) ^ qs;
                uint2 pk;
                pk.x = pack2(e0, e1);
                pk.y = pack2(e2, e3);
                *(uint2*)&Es[q * 128 + c * 8 + (key0 & 7)] = pk;
                p += (e0 + e1) + (e2 + e3);
            }
            rp[i] += p;
        }
        __syncthreads();

        // ---- PV (unchanged) ----
        #pragma unroll
        for (int ks2 = 0; ks2 < 4; ++ks2) {
            const int vch = (ks2 * 4 + qd) ^ (ln & 7);
            bfrag ea[4], vb[2];
            #pragma unroll
            for (int i = 0; i < 4; ++i) {
                const int q = wm + i*16 + ln;
                const int cs = (ks2*4 + qd) ^ (q & 7);
                ea[i] = *(const bfrag*)&Es[q * 128 + cs * 8];
            }
            #pragma unroll
            for (int j = 0; j < 2; ++j)
                vb[j] = *(const bfrag*)&VTs[(wnd + j*16 + ln) * 128 + vch * 8];
            #pragma unroll
            for (int i = 0; i < 4; ++i)
                #pragma unroll
                for (int j = 0; j < 2; ++j)
                    oacc[i][j] = __builtin_amdgcn_mfma_f32_16x16x32_bf16(
                        ea[i], vb[j], oacc[i][j], 0, 0, 0);
        }
    }

    // ---- deferred reduction across qd groups (lanes ln+16k share q) ----
    #pragma unroll
    for (int i = 0; i < 4; ++i) {
        float p = rp[i];
        p += __shfl_xor(p, 16);
        p += __shfl_xor(p, 32);
        rp[i] = p;
    }

    __syncthreads();
    float* rsls = (float*)Ks;
    if (qd == 0) {
        #pragma unroll
        for (int i = 0; i < 4; ++i)
            rsls[(w >> 1) * 128 + wm + i*16 + ln] = rp[i];
    }
    __syncthreads();
    if (tid < 128) {
        const float t = rsls[tid] + rsls[128 + tid];
        RSp[(size_t)(b * NH + h) * SL + qt * 128 + tid] = t;
        rsls[tid] = t;
    }
    __syncthreads();

    #pragma unroll
    for (int i = 0; i < 4; ++i) {
        #pragma unroll
        for (int r = 0; r < 4; ++r) {
            const int q = wm + i*16 + qd*4 + r;
            const float inv = 1.f / rsls[q];
            const size_t rowo = ((size_t)(b*SL + qt*128 + q)) * DM + h*DH;
            #pragma unroll
            for (int j = 0; j < 2; ++j)
                AOp[rowo + wnd + j*16 + ln] = f2bf(oacc[i][j][r] * inv);
        }
    }
}

// ---------------------------------------------------------------------------
// avg_attn body: one 64x64 avga tile, 16-head loop (round-0 structure).
// Caller provides >= 16640 B of LDS.
// ---------------------------------------------------------------------------
__device__ __forceinline__ void avg3_body(void* smem_, const int kt,
                                          const int qt, const int b,
                                          const ushort* __restrict__ Qm,
                                          const ushort* __restrict__ Km,
                                          const float* __restrict__ RS,
                                          float* __restrict__ avga)
{
    ushort* Qs = (ushort*)smem_;          // 64*64
    ushort* Kt = Qs + 64 * 64;            // 64*64
    float* rss = (float*)(Kt + 64 * 64);  // 64
    const int tid  = threadIdx.x;
    const int w    = tid >> 6;
    const int lane = tid & 63;
    const int ln   = lane & 15, qd = lane >> 4;
    const int wq = (w & 1) * 32, wk = (w >> 1) * 32;

    const int arow = lane >> 3;
    const int kc8s = ((lane & 7) ^ arow) * 8;

    float acc[2][2][4];
    #pragma unroll
    for (int i = 0; i < 2; ++i)
        #pragma unroll
        for (int j = 0; j < 2; ++j)
            #pragma unroll
            for (int r = 0; r < 4; ++r)
                acc[i][j][r] = 0.f;

    for (int h = 0; h < NH; ++h) {
        const size_t ho = ((size_t)(b * NH + h)) * SL * DH;
        __syncthreads();
        #pragma unroll
        for (int t = 0; t < 2; ++t) {
            const int c = w * 2 + t;
            gload16(Qm + ho + (size_t)(qt*64 + c*8 + arow) * DH + kc8s, &Qs[c * 512]);
            gload16(Km + ho + (size_t)(kt*64 + c*8 + arow) * DH + kc8s, &Kt[c * 512]);
        }
        if (tid < 64) rss[tid] = RS[(size_t)(b*NH + h)*SL + qt*64 + tid];
        __syncthreads();

        facc s[2][2];
        #pragma unroll
        for (int i = 0; i < 2; ++i)
            #pragma unroll
            for (int j = 0; j < 2; ++j)
                s[i][j] = (facc){0.f, 0.f, 0.f, 0.f};
        #pragma unroll
        for (int ks = 0; ks < 2; ++ks) {
            const int ch = (ks * 4 + qd) ^ (ln & 7);
            bfrag qa[2], kb[2];
            #pragma unroll
            for (int i = 0; i < 2; ++i)
                qa[i] = *(const bfrag*)&Qs[(wq + i*16 + ln) * 64 + ch * 8];
            #pragma unroll
            for (int j = 0; j < 2; ++j)
                kb[j] = *(const bfrag*)&Kt[(wk + j*16 + ln) * 64 + ch * 8];
            #pragma unroll
            for (int i = 0; i < 2; ++i)
                #pragma unroll
                for (int j = 0; j < 2; ++j)
                    s[i][j] = __builtin_amdgcn_mfma_f32_16x16x32_bf16(
                        qa[i], kb[j], s[i][j], 0, 0, 0);
        }
        #pragma unroll
        for (int i = 0; i < 2; ++i) {
            #pragma unroll
            for (int r = 0; r < 4; ++r) {
                const float ir = 0.0625f / rss[wq + i*16 + qd*4 + r];
                #pragma unroll
                for (int j = 0; j < 2; ++j)
                    acc[i][j][r] += __expf(s[i][j][r] * 0.015625f) * ir;
            }
        }
    }
    #pragma unroll
    for (int i = 0; i < 2; ++i) {
        #pragma unroll
        for (int r = 0; r < 4; ++r) {
            const int q = wq + i*16 + qd*4 + r;
            #pragma unroll
            for (int j = 0; j < 2; ++j)
                avga[((size_t)(b*SL + qt*64 + q)) * SL + kt*64 + wk + j*16 + ln]
                    = acc[i][j][r];
        }
    }
}

// ---------------------------------------------------------------------------
// mid_k: interleave the two INDEPENDENT post-attention jobs so each CU
// co-hosts one MFMA-bound Wo-GEMM block and one latency-bound avg3 block
// (complementary pipes -> overlap). Even blocks = Wo-GEMM tile, odd = avg3.
// (round-8 proven configuration: 64 KB smem, 2 blocks/CU)
// Disjointness: avg3 reads Qb[first half], Kb[second half], RS; Wo reads
// AOt/AOi/WoT, writes out rows + bf16 side-copy to Kb[first half].
// ---------------------------------------------------------------------------
__global__ __launch_bounds__(256, 2)
void mid_k(const ushort* __restrict__ AOt, const ushort* __restrict__ AOi,
           const ushort* __restrict__ WoT, const float* __restrict__ bo,
           float* __restrict__ text_cross, ushort* __restrict__ tcb,
           const ushort* __restrict__ Qm, const ushort* __restrict__ Km,
           const float* __restrict__ RS, float* __restrict__ avga)
{
    __shared__ char smem[65536];
    const int bid = blockIdx.x;
    if (bid & 1) {
        const int la = bid >> 1;           // [0,512): kt fastest, then qt, b
        avg3_body(smem, la & 7, (la >> 3) & 7, la >> 6, Qm, Km, RS, avga);
    } else {
        gemm_body<0, 5, 4>(smem, bid >> 1, 8, 64,
            AOt, AOt, nullptr, nullptr, DM, DM, DM, DM, DM,
            AOi, 4096, WoT, DM, bo, nullptr, nullptr,
            text_cross, tcb, nullptr, nullptr, 0);
    }
}

// ---------------------------------------------------------------------------
extern "C" void kernel_launch(void* const* d_in, const int* in_sizes, int n_in,
                              void* d_out, int out_size, void* d_ws, size_t ws_size,
                              hipStream_t stream)
{
    (void)in_sizes; (void)n_in; (void)out_size;
    const float* text  = (const float*)d_in[0];
    const float* image = (const float*)d_in[1];
    const float* Wq = (const float*)d_in[2];
    const float* bq = (const float*)d_in[3];
    const float* Wk = (const float*)d_in[4];
    const float* bk = (const float*)d_in[5];
    const float* Wv = (const float*)d_in[6];
    const float* bv = (const float*)d_in[7];
    const float* Wo = (const float*)d_in[8];
    const float* bo = (const float*)d_in[9];
    const float* W1 = (const float*)d_in[10];
    const float* b1 = (const float*)d_in[11];
    const float* W2 = (const float*)d_in[12];
    const float* b2 = (const float*)d_in[13];
    float* out = (float*)d_out;

    const size_t SZ   = (size_t)NB * SL * DM;   // 4,194,304
    const size_t HALF = SZ;

    // ---- fixed workspace layout (bf16 = ushort), ~82.1 MB ----
    ushort* xbf = (ushort*)d_ws;        // [8192,1024] text 0..4095, image 4096..
    ushort* Qb  = xbf + 2*SZ;           // [16,NH,SL,DH]
    ushort* Kb  = Qb  + 2*SZ;           // [16,NH,SL,DH]; later bf16 text_cross
    ushort* VT  = Kb  + 2*SZ;           // [16,NH,DH,SL]
    ushort* AOt = VT  + 2*SZ;           // [4096,1024]
    ushort* Wt  = AOt + SZ;             // Wq^T|Wk^T|Wv^T, later W1^T (fallback)
    float*  RS  = (float*)(Wt + 3*DM*DM);   // [8,NH,SL]
    char*   wsEnd = (char*)(RS + NB*NH*SL);
    ushort* hidden = Qb;                // reuses Q (dead after mid_k)

    float* text_cross = out;            // Wo gemm writes rows 0..8191 (both)
    float* comp       = out + 2*SZ;
    float* avga       = out + 3*SZ;

    // ---- scratch tiers ----
    // tier A (round-7 proven): RS2, WoT, AOi, W2T in ws
    // tier B (round-8 proven): + W1T slot -> W1/W2 transposes fold into prep_k
    const size_t extA = (size_t)NB*NH*SL*4 + (size_t)DM*DM*2
                      + (size_t)SZ*2 + (size_t)DM*DM*2;
    const size_t extB = extA + (size_t)3*DM*DM*2;
    const size_t fixBytes = (size_t)(wsEnd - (char*)d_ws);
    float* RS2; ushort* WoT; ushort* AOi; ushort* W2T; ushort* W1Tx;
    const bool haveA = (ws_size >= fixBytes + extA);
    const bool haveB = (ws_size >= fixBytes + extB);
    if (haveA) {
        RS2 = (float*)wsEnd;
        WoT = (ushort*)(RS2 + NB*NH*SL);
        AOi = WoT + DM*DM;
        W2T = AOi + SZ;
        W1Tx = haveB ? (W2T + DM*DM) : Wt;
    } else {                            // fallback (correctness-first)
        WoT = (ushort*)comp;
        AOi = WoT + DM*DM;
        RS2 = (float*)Wt;
        W2T = AOt;                      // dead after Wo gemm (inside mid_k)
        W1Tx = Wt;
    }

    const dim3 blk(256);

    // ---- prep: cvt + Wq/Wk/Wv/Wo transposes [+ W1/W2 when tier B] ----
    prep_k<<<haveB ? 10240 : 9216, blk, 0, stream>>>(
        text, image, Wq, Wk, Wv, Wo, W1, W2, xbf, Wt, WoT, W1Tx, W2T);

    // ---- fused Q/K/V projection: M=8192, N=3072 ----
    // 8-wave (512 thr): 2 blocks/CU x 8 waves = 4 waves/SIMD (was 2) --
    // same BK=64 barrier structure, double the latency-hiding wave pool.
    mfma_gemm<0,4,8><<<dim3(24,64), dim3(512), 0, stream>>>(
        xbf, xbf, nullptr, nullptr, DM, DM, DM, DM, DM, nullptr, 0,
        Wt, DM, bq, bk, bv, nullptr, Qb, Kb, VT, 1);

    // ---- both attention directions (1D grid, XCD-pair swizzle) ----
    attn2m_k<<<dim3(1024), blk, 0, stream>>>(Qb, Kb, VT, AOt, AOi, RS, RS2);

    // ---- mid: avg3 (odd) interleaved with Wo gemm (even) ----
    mid_k<<<1024, blk, 0, stream>>>(AOt, AOi, WoT, bo, text_cross, Kb,
                                    Qb, Kb + HALF, RS, avga);
    if (!haveB)   // W1/W2 transposes not folded into prep
        tconvW12_k<<<1024, blk, 0, stream>>>(W1, W2, W1Tx, W2T);

    // ---- MLP (8-wave GEMMs: proven round-8 config) ----
    mfma_gemm<2,2,8><<<dim3(8,32), dim3(512), 0, stream>>>(
        xbf, xbf + SZ, nullptr, Kb, DM, 2*DM, 3*DM, DM, DM, nullptr, 0,
        W1Tx, 3*DM, b1, nullptr, nullptr, nullptr, hidden, nullptr, nullptr, 0);
    mfma_gemm<0,0,8><<<dim3(8,32), dim3(512), 0, stream>>>(
        hidden, hidden, nullptr, nullptr, DM, DM, DM, DM, DM, nullptr, 0,
        W2T, DM, b2, nullptr, nullptr, comp, nullptr, nullptr, nullptr, 0);
}

// Round 12
// 321.759 us; speedup vs baseline: 1.0440x; 1.0375x over previous
//
#include <hip/hip_runtime.h>

#define NB 8
#define SL 512
#define DM 1024
#define NH 16
#define DH 64

using bfrag = __attribute__((ext_vector_type(8))) short;   // 8 bf16 (4 VGPRs)
using facc  = __attribute__((ext_vector_type(4))) float;   // 4 fp32 acc

__device__ __forceinline__ float bf2f(ushort u) {
    return __uint_as_float(((unsigned)u) << 16);
}
__device__ __forceinline__ ushort f2bf(float f) {
    unsigned x = __float_as_uint(f);
    return (ushort)((x + 0x7FFFu + ((x >> 16) & 1u)) >> 16);   // RNE
}
__device__ __forceinline__ unsigned pack2(float a, float b) {
    return (unsigned)f2bf(a) | ((unsigned)f2bf(b) << 16);
}
__device__ __forceinline__ void gload16(const ushort* g, ushort* l) {
    __builtin_amdgcn_global_load_lds(
        (const __attribute__((address_space(1))) unsigned*)g,
        (__attribute__((address_space(3))) unsigned*)l, 16, 0, 0);
}

// ---------------------------------------------------------------------------
// Transpose-convert body: W[R,C] fp32 -> WT[C,R] bf16, one 64x64 tile.
// Caller provides >= 8704 B of LDS.
// ---------------------------------------------------------------------------
__device__ __forceinline__ void tconv_body(void* smem_,
                                           const float* __restrict__ W,
                                           ushort* __restrict__ WT,
                                           const int R, const int C,
                                           const int c0, const int r0) {
    ushort (*T)[68] = (ushort (*)[68])smem_;
    const int tid = threadIdx.x;
    #pragma unroll
    for (int rr = 0; rr < 4; ++rr) {
        const int r = (tid >> 4) + rr * 16;
        const int c4 = (tid & 15) * 4;
        const float4 f = *(const float4*)(W + (size_t)(r0 + r) * C + c0 + c4);
        T[c4+0][r] = f2bf(f.x); T[c4+1][r] = f2bf(f.y);
        T[c4+2][r] = f2bf(f.z); T[c4+3][r] = f2bf(f.w);
    }
    __syncthreads();
    #pragma unroll
    for (int rr = 0; rr < 4; ++rr) {
        const int c = (tid >> 4) + rr * 16;
        const int r4 = (tid & 15) * 4;
        *(ushort4*)(WT + (size_t)(c0 + c) * R + r0 + r4) =
            make_ushort4(T[c][r4+0], T[c][r4+1], T[c][r4+2], T[c][r4+3]);
    }
}

// ---------------------------------------------------------------------------
// prep: cvt text+image (0..8191) + transpose Wq/Wk/Wv/Wo (8192..9215)
// [+ W1/W2 (9216..10239) when launched with the extended grid].
// ---------------------------------------------------------------------------
__global__ __launch_bounds__(256)
void prep_k(const float* __restrict__ text, const float* __restrict__ image,
            const float* __restrict__ Wq, const float* __restrict__ Wk,
            const float* __restrict__ Wv, const float* __restrict__ Wo,
            const float* __restrict__ W1, const float* __restrict__ W2,
            ushort* __restrict__ xbf, ushort* __restrict__ Wt,
            ushort* __restrict__ WoT, ushort* __restrict__ W1T,
            ushort* __restrict__ W2T)
{
    __shared__ ushort Tbuf[64][68];
    const int bid = blockIdx.x;
    const size_t SZc = (size_t)NB * SL * DM;
    if (bid < 8192) {
        const int half = bid >> 12;
        const float* s = half ? image : text;
        ushort* d = xbf + (size_t)half * SZc;
        const size_t i = ((size_t)(bid & 4095) * 256 + threadIdx.x) * 4;
        const float4 f = *(const float4*)(s + i);
        *(ushort4*)(d + i) =
            make_ushort4(f2bf(f.x), f2bf(f.y), f2bf(f.z), f2bf(f.w));
    } else if (bid < 9216) {
        const int t = bid - 8192;
        const int wsel = t >> 8, tt = t & 255;
        const float* W = (wsel == 0) ? Wq : (wsel == 1) ? Wk
                       : (wsel == 2) ? Wv : Wo;
        ushort* WT = (wsel < 3) ? Wt + (size_t)wsel * DM * DM : WoT;
        tconv_body(Tbuf, W, WT, DM, DM, (tt & 15) * 64, (tt >> 4) * 64);
    } else {
        const int t = bid - 9216;
        if (t < 768)
            tconv_body(Tbuf, W1, W1T, 3 * DM, DM, (t & 15) * 64, (t >> 4) * 64);
        else {
            const int u = t - 768;
            tconv_body(Tbuf, W2, W2T, DM, DM, (u & 15) * 64, (u >> 4) * 64);
        }
    }
}

// ---------------------------------------------------------------------------
// W1 [3072,1024] (blocks 0..767) + W2 [1024,1024] (768..1023) transposes.
// (fallback path only; extended path folds these into prep_k)
// ---------------------------------------------------------------------------
__global__ __launch_bounds__(256)
void tconvW12_k(const float* __restrict__ W1, const float* __restrict__ W2,
                ushort* __restrict__ W1T, ushort* __restrict__ W2T)
{
    __shared__ ushort Tbuf[64][68];
    const int bid = blockIdx.x;
    if (bid < 768)
        tconv_body(Tbuf, W1, W1T, 3 * DM, DM, (bid & 15) * 64, (bid >> 4) * 64);
    else {
        const int t = bid - 768;
        tconv_body(Tbuf, W2, W2T, DM, DM, (t & 15) * 64, (t >> 4) * 64);
    }
}

// ---------------------------------------------------------------------------
// bf16 MFMA GEMM body: 128x128 tile, WAVES in {4,8}, BK=64, double-buffered
// LDS staging (one barrier per K-iter; stage(k+1) overlaps compute(k)).
// WAVES=4: 2x2 waves of 64x64 (acc 4x4), 2 blocks/CU (QKV, Wo).
// WAVES=8: 2x4 waves of 64x32 (acc 4x2), 512 thr -> 2 waves/SIMD at the
//   MLP grids' 1 block/CU (round-8 proven; round-9 BK=32 and round-10
//   8-wave-QKV both regressed totals -- this is the terminal config).
//   out[m,n] = ACT( sum_k A[m,k]*B[k,n] + bias[n] ),  B given as BT[n,k].
// A K-concat: A0 | A1 (bf16) | third segment = A2b (bf16) if non-null else
// A2f (fp32 load+convert). M-concat: rows >= Msplit from AM1 (block-uniform).
// XCD swizzle on logical index L. OMODE 0: fp32 row-major. 2: bf16.
// 4: fused QKV epilogue. 5: fp32 + bf16 side-copy.
// Caller provides 64 KB LDS.
// ---------------------------------------------------------------------------
template<int ACT, int OMODE, int WAVES>
__device__ __forceinline__ void gemm_body(
    void* smem_, const int L, const int NTg, const int MTg,
    const ushort* __restrict__ A0, const ushort* __restrict__ A1,
    const float* __restrict__ A2f, const ushort* __restrict__ A2b,
    const int KA1, const int KA2, const int Ktot,
    const int lda, const int ldaf,
    const ushort* __restrict__ AM1, const int Msplit,
    const ushort* __restrict__ BT, const int ldb,
    const float* __restrict__ bias, const float* __restrict__ biasK,
    const float* __restrict__ biasV,
    float* __restrict__ outf, ushort* __restrict__ outb,
    ushort* __restrict__ outbK, ushort* __restrict__ outbVT,
    const int clustN)
{
    constexpr int NJ = (WAVES == 4) ? 4 : 2;   // n-frags per wave
    constexpr int TC = 16 / WAVES;             // stage chunk iters per wave
    ushort* sh = (ushort*)smem_;   // 2 buffers x (As 8192 + Bs 8192), 64 KB
    const int tid  = threadIdx.x;
    const int w    = tid >> 6;
    const int lane = tid & 63;
    const int ln   = lane & 15, qd = lane >> 4;
    const int wm = (w & 1) * 64;
    const int wn = (WAVES == 4) ? (w >> 1) * 64 : (w >> 1) * 32;

    // ---- XCD-clustered block swizzle ----
    const int xcd = L & 7, sIdx = L >> 3;
    int mt, nt;
    if (clustN) { const int np = NTg >> 3; nt = xcd * np + sIdx % np; mt = sIdx / np; }
    else        { mt = xcd * (MTg >> 3) + sIdx / NTg; nt = sIdx - (sIdx / NTg) * NTg; }
    const int m0 = mt * 128, n0 = nt * 128;

    // ---- M-concat source select (block-uniform) ----
    const ushort* A0u = A0; const ushort* A1u = A1; int m0A = m0;
    if (Msplit && m0 >= Msplit) { A0u = AM1; A1u = AM1; m0A = m0 - Msplit; }

    const int arow = (lane >> 3);               // row-in-chunk 0..7
    const int kc8s = ((lane & 7) ^ arow) * 8;   // swizzled global k-chunk

    facc acc[4][NJ];
    #pragma unroll
    for (int i = 0; i < 4; ++i)
        #pragma unroll
        for (int j = 0; j < NJ; ++j)
            acc[i][j] = (facc){0.f, 0.f, 0.f, 0.f};

    auto stage = [&](int k0, ushort* buf) {
        ushort* Asb = buf;
        ushort* Bsb = buf + 8192;
        #pragma unroll
        for (int t = 0; t < TC; ++t) {
            const int c = w * TC + t;
            gload16(BT + (size_t)(n0 + c * 8 + arow) * ldb + k0 + kc8s,
                    &Bsb[c * 512]);
        }
        if (k0 < KA2) {
            const ushort* Ab; int ko;
            if (k0 < KA1) { Ab = A0u; ko = k0; }
            else          { Ab = A1u; ko = k0 - KA1; }
            #pragma unroll
            for (int t = 0; t < TC; ++t) {
                const int c = w * TC + t;
                gload16(Ab + (size_t)(m0A + c * 8 + arow) * lda + ko + kc8s,
                        &Asb[c * 512]);
            }
        } else if (A2b) {  // bf16 third segment (direct to LDS)
            const int ko = k0 - KA2;
            #pragma unroll
            for (int t = 0; t < TC; ++t) {
                const int c = w * TC + t;
                gload16(A2b + (size_t)(m0A + c * 8 + arow) * ldaf + ko + kc8s,
                        &Asb[c * 512]);
            }
        } else {           // fp32 source: load + convert + ds_write
            const int ko = k0 - KA2;
            #pragma unroll
            for (int t = 0; t < TC; ++t) {
                const int c = w * TC + t;
                const float* src = A2f + (size_t)(m0A + c * 8 + arow) * ldaf + ko + kc8s;
                const float4 f0 = *(const float4*)src;
                const float4 f1 = *(const float4*)(src + 4);
                uint4 p;
                p.x = pack2(f0.x, f0.y); p.y = pack2(f0.z, f0.w);
                p.z = pack2(f1.x, f1.y); p.w = pack2(f1.z, f1.w);
                *(uint4*)&Asb[c * 512 + lane * 8] = p;
            }
        }
    };

    stage(0, sh);
    for (int k0 = 0; k0 < Ktot; k0 += 64) {
        ushort* cur = sh + ((k0 >> 6) & 1) * 16384;
        ushort* nxt = sh + (((k0 >> 6) & 1) ^ 1) * 16384;
        __syncthreads();                       // drains stage(k0) (vmcnt+lgkm)
        if (k0 + 64 < Ktot) stage(k0 + 64, nxt);   // overlaps compute below
        ushort* Asb = cur;
        ushort* Bsb = cur + 8192;
        #pragma unroll
        for (int ks = 0; ks < 2; ++ks) {
            const int ch = (ks * 4 + qd) ^ (ln & 7);   // swizzled chunk
            bfrag af[4], bfv[NJ];
            #pragma unroll
            for (int i = 0; i < 4; ++i)
                af[i] = *(const bfrag*)&Asb[(wm + i*16 + ln) * 64 + ch * 8];
            #pragma unroll
            for (int j = 0; j < NJ; ++j)
                bfv[j] = *(const bfrag*)&Bsb[(wn + j*16 + ln) * 64 + ch * 8];
            #pragma unroll
            for (int i = 0; i < 4; ++i)
                #pragma unroll
                for (int j = 0; j < NJ; ++j)
                    acc[i][j] = __builtin_amdgcn_mfma_f32_16x16x32_bf16(
                        af[i], bfv[j], acc[i][j], 0, 0, 0);
        }
    }

    if constexpr (OMODE == 4) {
        const int seg   = n0 >> 10;        // 0=Q 1=K 2=V (block-uniform)
        const int nloc0 = n0 & 1023;
        const float* bs = (seg == 0) ? bias : (seg == 1) ? biasK : biasV;
        if (seg < 2) {
            ushort* ob = (seg == 0) ? outb : outbK;
            #pragma unroll
            for (int j = 0; j < NJ; ++j) {
                const int nl = nloc0 + wn + j * 16 + ln;
                const float bn = bs[nl];
                #pragma unroll
                for (int i = 0; i < 4; ++i) {
                    const int mb = m0 + wm + i * 16 + qd * 4;
                    #pragma unroll
                    for (int r = 0; r < 4; ++r) {
                        const float v = 1.f / (1.f + __expf(-(acc[i][j][r] + bn)));
                        const int m = mb + r;
                        const int g = m >> 9, l = m & 511;
                        ob[(((size_t)(g * NH + (nl >> 6))) * SL + l) * DH + (nl & 63)]
                            = f2bf(v);
                    }
                }
            }
        } else {
            // V: in-LDS swizzled transpose -> [g,h,d,l] coalesced stores
            __syncthreads();
            #pragma unroll
            for (int j = 0; j < NJ; ++j) {
                const int n_l = wn + j * 16 + ln;
                const float bn = bs[nloc0 + n_l];
                #pragma unroll
                for (int i = 0; i < 4; ++i) {
                    #pragma unroll
                    for (int r = 0; r < 4; ++r) {
                        const int m_l = wm + i * 16 + qd * 4 + r;
                        const int c = (m_l >> 3) ^ (n_l & 7);
                        sh[n_l * 128 + c * 8 + (m_l & 7)] = f2bf(acc[i][j][r] + bn);
                    }
                }
            }
            __syncthreads();
            const int n_l = tid >> 1, half = tid & 1;
            const int nl = nloc0 + n_l;
            const int g = m0 >> 9, l0 = m0 & 511;
            ushort* dst = outbVT +
                (((size_t)(g * NH + (nl >> 6))) * DH + (nl & 63)) * SL + l0;
            #pragma unroll
            for (int u = 0; u < 8; ++u) {
                const int c = half * 8 + u;
                const int cs = c ^ (n_l & 7);
                *(uint4*)(dst + c * 8) = *(const uint4*)&sh[n_l * 128 + cs * 8];
            }
        }
        return;
    } else {
        // ---- standard epilogue: C/D layout col=lane&15, row=qd*4+r ----
        #pragma unroll
        for (int j = 0; j < NJ; ++j) {
            const int n = n0 + wn + j * 16 + ln;
            const float bn = bias[n];
            #pragma unroll
            for (int i = 0; i < 4; ++i) {
                const int mb = m0 + wm + i * 16 + qd * 4;
                #pragma unroll
                for (int r = 0; r < 4; ++r) {
                    float v = acc[i][j][r] + bn;
                    if (ACT == 1)      v = 1.f / (1.f + __expf(-v));
                    else if (ACT == 2) v = v > 0.f ? v : 0.f;
                    const int m = mb + r;
                    if (OMODE == 0)      outf[(size_t)m * DM + n] = v;
                    else if (OMODE == 2) outb[(size_t)m * DM + n] = f2bf(v);
                    else {               // OMODE == 5: fp32 + bf16 side-copy
                        outf[(size_t)m * DM + n] = v;
                        if (m < Msplit) outb[(size_t)m * DM + n] = f2bf(v);
                    }
                }
            }
        }
    }
}

// ---------------------------------------------------------------------------
// Standalone GEMM kernel wrapper.
// ---------------------------------------------------------------------------
template<int ACT, int OMODE, int WAVES>
__global__ __launch_bounds__(WAVES * 64, 2)
void mfma_gemm(const ushort* __restrict__ A0, const ushort* __restrict__ A1,
               const float* __restrict__ A2f, const ushort* __restrict__ A2b,
               const int KA1, const int KA2, const int Ktot,
               const int lda, const int ldaf,
               const ushort* __restrict__ AM1, const int Msplit,
               const ushort* __restrict__ BT, const int ldb,
               const float* __restrict__ bias, const float* __restrict__ biasK,
               const float* __restrict__ biasV,
               float* __restrict__ outf, ushort* __restrict__ outb,
               ushort* __restrict__ outbK, ushort* __restrict__ outbVT,
               const int clustN)
{
    __shared__ char smem[65536];
    gemm_body<ACT, OMODE, WAVES>(smem, blockIdx.x + gridDim.x * blockIdx.y,
                                 gridDim.x, gridDim.y,
                                 A0, A1, A2f, A2b, KA1, KA2, Ktot, lda, ldaf,
                                 AM1, Msplit, BT, ldb, bias, biasK, biasV,
                                 outf, outb, outbK, outbVT, clustN);
}

// ---------------------------------------------------------------------------
// MFMA fuzzy attention, both directions, 1D grid of 1024 blocks.
// (frozen at round-6 structure: swapped QK^T, packed b64 Es writes, in-lane
// partial row sums, XCD-pair K/V locality. See round-6 notes.)
// LDS = 16K (Ks) + 16K (VTs) + 32K (Es) = 64 KB -> 2 blocks/CU.
// ---------------------------------------------------------------------------
__global__ __launch_bounds__(256, 2)
void attn2m_k(const ushort* __restrict__ Qm, const ushort* __restrict__ Km,
              const ushort* __restrict__ VTm, ushort* __restrict__ AO0,
              ushort* __restrict__ AO1, float* __restrict__ RS0,
              float* __restrict__ RS1)
{
    __shared__ ushort Ks[128 * 64];
    __shared__ ushort VTs[64 * 128];
    __shared__ ushort Es[128 * 128];
    const int tid  = threadIdx.x;
    const int w    = tid >> 6;
    const int lane = tid & 63;
    const int ln   = lane & 15, qd = lane >> 4;
    const int wm  = (w & 1) * 64;          // q offset of this wave
    const int wns = (w >> 1) * 64;         // key offset (S stage)
    const int wnd = (w >> 1) * 32;         // d offset (PV stage)

    // ---- XCD-pair decode: qt fastest WITHIN an xcd ----
    const int L   = blockIdx.x;
    const int xcd = L & 7, s = L >> 3;     // s in [0,128)
    const int qt  = s & 3;
    const int pid = xcd * 32 + (s >> 2);   // pair id in [0,256)
    const int h   = pid & 15;
    const int zz  = pid >> 4;              // [0,16)
    const int dir = zz >> 3, b = zz & 7;

    const size_t HALFc = (size_t)NB * SL * DM;
    const ushort* Qall = Qm  + (dir ? HALFc : 0);
    const ushort* Kall = Km  + (dir ? 0 : HALFc);
    const ushort* Vall = VTm + (dir ? 0 : HALFc);
    ushort* AOp = dir ? AO1 : AO0;
    float*  RSp = dir ? RS1 : RS0;

    const size_t ho = ((size_t)(b * NH + h)) * SL * DH;
    const ushort* Qg  = Qall + ho + (size_t)qt * 128 * DH;
    const ushort* Kg  = Kall + ho;
    const ushort* VTg = Vall + ho;

    bfrag qf[4][2];
    #pragma unroll
    for (int i = 0; i < 4; ++i)
        #pragma unroll
        for (int ks = 0; ks < 2; ++ks)
            qf[i][ks] = *(const bfrag*)(Qg + (size_t)(wm + i*16 + ln) * DH + ks*32 + qd*8);

    facc oacc[4][2];
    #pragma unroll
    for (int i = 0; i < 4; ++i)
        #pragma unroll
        for (int j = 0; j < 2; ++j)
            oacc[i][j] = (facc){0.f, 0.f, 0.f, 0.f};
    float rp[4];   // per-lane partial row sums, q = wm + i*16 + ln
    #pragma unroll
    for (int i = 0; i < 4; ++i)
        rp[i] = 0.f;

    const int arow = lane >> 3;
    const int kc8s = ((lane & 7) ^ arow) * 8;
    const int vrow = lane >> 4;

    for (int kc = 0; kc < 4; ++kc) {
        __syncthreads();
        #pragma unroll
        for (int t = 0; t < 4; ++t) {
            const int c = w * 4 + t;
            const int vc8s = ((lane & 15) ^ ((c * 4 + vrow) & 7)) * 8;
            gload16(Kg + (size_t)(kc*128 + c*8 + arow) * DH + kc8s, &Ks[c * 512]);
            gload16(VTg + (size_t)(c*4 + vrow) * SL + kc*128 + vc8s, &VTs[c * 512]);
        }
        __syncthreads();

        // ---- swapped QK^T: sacc[j][i] = D[row=key][col=q] ----
        facc sacc[4][4];
        #pragma unroll
        for (int j = 0; j < 4; ++j)
            #pragma unroll
            for (int i = 0; i < 4; ++i)
                sacc[j][i] = (facc){0.f, 0.f, 0.f, 0.f};
        #pragma unroll
        for (int ks = 0; ks < 2; ++ks) {
            const int ch = (ks * 4 + qd) ^ (ln & 7);
            bfrag kf[4];
            #pragma unroll
            for (int j = 0; j < 4; ++j)
                kf[j] = *(const bfrag*)&Ks[(wns + j*16 + ln) * 64 + ch * 8];
            #pragma unroll
            for (int j = 0; j < 4; ++j)
                #pragma unroll
                for (int i = 0; i < 4; ++i)
                    sacc[j][i] = __builtin_amdgcn_mfma_f32_16x16x32_bf16(
                        kf[j], qf[i][ks], sacc[j][i], 0, 0, 0);
        }

        // ---- exp + packed Es write (b64) + in-lane partial row sum ----
        #pragma unroll
        for (int i = 0; i < 4; ++i) {
            const int q  = wm + i*16 + ln;
            const int qs = q & 7;
            float p = 0.f;
            #pragma unroll
            for (int j = 0; j < 4; ++j) {
                const int key0 = wns + j*16 + qd*4;   // 4 consecutive keys
                const float e0 = __expf(sacc[j][i][0] * 0.015625f);
                const float e1 = __expf(sacc[j][i][1] * 0.015625f);
                const float e2 = __expf(sacc[j][i][2] * 0.015625f);
                const float e3 = __expf(sacc[j][i][3] * 0.015625f);
                const int c = ((key0 & 127) >> 3) ^ qs;
                uint2 pk;
                pk.x = pack2(e0, e1);
                pk.y = pack2(e2, e3);
                *(uint2*)&Es[q * 128 + c * 8 + (key0 & 7)] = pk;
                p += (e0 + e1) + (e2 + e3);
            }
            rp[i] += p;
        }
        __syncthreads();

        // ---- PV (unchanged) ----
        #pragma unroll
        for (int ks2 = 0; ks2 < 4; ++ks2) {
            const int vch = (ks2 * 4 + qd) ^ (ln & 7);
            bfrag ea[4], vb[2];
            #pragma unroll
            for (int i = 0; i < 4; ++i) {
                const int q = wm + i*16 + ln;
                const int cs = (ks2*4 + qd) ^ (q & 7);
                ea[i] = *(const bfrag*)&Es[q * 128 + cs * 8];
            }
            #pragma unroll
            for (int j = 0; j < 2; ++j)
                vb[j] = *(const bfrag*)&VTs[(wnd + j*16 + ln) * 128 + vch * 8];
            #pragma unroll
            for (int i = 0; i < 4; ++i)
                #pragma unroll
                for (int j = 0; j < 2; ++j)
                    oacc[i][j] = __builtin_amdgcn_mfma_f32_16x16x32_bf16(
                        ea[i], vb[j], oacc[i][j], 0, 0, 0);
        }
    }

    // ---- deferred reduction across qd groups (lanes ln+16k share q) ----
    #pragma unroll
    for (int i = 0; i < 4; ++i) {
        float p = rp[i];
        p += __shfl_xor(p, 16);
        p += __shfl_xor(p, 32);
        rp[i] = p;
    }

    __syncthreads();
    float* rsls = (float*)Ks;
    if (qd == 0) {
        #pragma unroll
        for (int i = 0; i < 4; ++i)
            rsls[(w >> 1) * 128 + wm + i*16 + ln] = rp[i];
    }
    __syncthreads();
    if (tid < 128) {
        const float t = rsls[tid] + rsls[128 + tid];
        RSp[(size_t)(b * NH + h) * SL + qt * 128 + tid] = t;
        rsls[tid] = t;
    }
    __syncthreads();

    #pragma unroll
    for (int i = 0; i < 4; ++i) {
        #pragma unroll
        for (int r = 0; r < 4; ++r) {
            const int q = wm + i*16 + qd*4 + r;
            const float inv = 1.f / rsls[q];
            const size_t rowo = ((size_t)(b*SL + qt*128 + q)) * DM + h*DH;
            #pragma unroll
            for (int j = 0; j < 2; ++j)
                AOp[rowo + wnd + j*16 + ln] = f2bf(oacc[i][j][r] * inv);
        }
    }
}

// ---------------------------------------------------------------------------
// avg_attn body: one 64x64 avga tile, 16-head loop (round-0 structure).
// Caller provides >= 16640 B of LDS.
// ---------------------------------------------------------------------------
__device__ __forceinline__ void avg3_body(void* smem_, const int kt,
                                          const int qt, const int b,
                                          const ushort* __restrict__ Qm,
                                          const ushort* __restrict__ Km,
                                          const float* __restrict__ RS,
                                          float* __restrict__ avga)
{
    ushort* Qs = (ushort*)smem_;          // 64*64
    ushort* Kt = Qs + 64 * 64;            // 64*64
    float* rss = (float*)(Kt + 64 * 64);  // 64
    const int tid  = threadIdx.x;
    const int w    = tid >> 6;
    const int lane = tid & 63;
    const int ln   = lane & 15, qd = lane >> 4;
    const int wq = (w & 1) * 32, wk = (w >> 1) * 32;

    const int arow = lane >> 3;
    const int kc8s = ((lane & 7) ^ arow) * 8;

    float acc[2][2][4];
    #pragma unroll
    for (int i = 0; i < 2; ++i)
        #pragma unroll
        for (int j = 0; j < 2; ++j)
            #pragma unroll
            for (int r = 0; r < 4; ++r)
                acc[i][j][r] = 0.f;

    for (int h = 0; h < NH; ++h) {
        const size_t ho = ((size_t)(b * NH + h)) * SL * DH;
        __syncthreads();
        #pragma unroll
        for (int t = 0; t < 2; ++t) {
            const int c = w * 2 + t;
            gload16(Qm + ho + (size_t)(qt*64 + c*8 + arow) * DH + kc8s, &Qs[c * 512]);
            gload16(Km + ho + (size_t)(kt*64 + c*8 + arow) * DH + kc8s, &Kt[c * 512]);
        }
        if (tid < 64) rss[tid] = RS[(size_t)(b*NH + h)*SL + qt*64 + tid];
        __syncthreads();

        facc s[2][2];
        #pragma unroll
        for (int i = 0; i < 2; ++i)
            #pragma unroll
            for (int j = 0; j < 2; ++j)
                s[i][j] = (facc){0.f, 0.f, 0.f, 0.f};
        #pragma unroll
        for (int ks = 0; ks < 2; ++ks) {
            const int ch = (ks * 4 + qd) ^ (ln & 7);
            bfrag qa[2], kb[2];
            #pragma unroll
            for (int i = 0; i < 2; ++i)
                qa[i] = *(const bfrag*)&Qs[(wq + i*16 + ln) * 64 + ch * 8];
            #pragma unroll
            for (int j = 0; j < 2; ++j)
                kb[j] = *(const bfrag*)&Kt[(wk + j*16 + ln) * 64 + ch * 8];
            #pragma unroll
            for (int i = 0; i < 2; ++i)
                #pragma unroll
                for (int j = 0; j < 2; ++j)
                    s[i][j] = __builtin_amdgcn_mfma_f32_16x16x32_bf16(
                        qa[i], kb[j], s[i][j], 0, 0, 0);
        }
        #pragma unroll
        for (int i = 0; i < 2; ++i) {
            #pragma unroll
            for (int r = 0; r < 4; ++r) {
                const float ir = 0.0625f / rss[wq + i*16 + qd*4 + r];
                #pragma unroll
                for (int j = 0; j < 2; ++j)
                    acc[i][j][r] += __expf(s[i][j][r] * 0.015625f) * ir;
            }
        }
    }
    #pragma unroll
    for (int i = 0; i < 2; ++i) {
        #pragma unroll
        for (int r = 0; r < 4; ++r) {
            const int q = wq + i*16 + qd*4 + r;
            #pragma unroll
            for (int j = 0; j < 2; ++j)
                avga[((size_t)(b*SL + qt*64 + q)) * SL + kt*64 + wk + j*16 + ln]
                    = acc[i][j][r];
        }
    }
}

// ---------------------------------------------------------------------------
// mid_k: interleave the two INDEPENDENT post-attention jobs so each CU
// co-hosts one MFMA-bound Wo-GEMM block and one latency-bound avg3 block
// (complementary pipes -> overlap). Even blocks = Wo-GEMM tile, odd = avg3.
// Disjointness: avg3 reads Qb[first half], Kb[second half], RS; Wo reads
// AOt/AOi/WoT, writes out rows + bf16 side-copy to Kb[first half].
// ---------------------------------------------------------------------------
__global__ __launch_bounds__(256, 2)
void mid_k(const ushort* __restrict__ AOt, const ushort* __restrict__ AOi,
           const ushort* __restrict__ WoT, const float* __restrict__ bo,
           float* __restrict__ text_cross, ushort* __restrict__ tcb,
           const ushort* __restrict__ Qm, const ushort* __restrict__ Km,
           const float* __restrict__ RS, float* __restrict__ avga)
{
    __shared__ char smem[65536];
    const int bid = blockIdx.x;
    if (bid & 1) {
        const int la = bid >> 1;           // [0,512): kt fastest, then qt, b
        avg3_body(smem, la & 7, (la >> 3) & 7, la >> 6, Qm, Km, RS, avga);
    } else {
        gemm_body<0, 5, 4>(smem, bid >> 1, 8, 64,
            AOt, AOt, nullptr, nullptr, DM, DM, DM, DM, DM,
            AOi, 4096, WoT, DM, bo, nullptr, nullptr,
            text_cross, tcb, nullptr, nullptr, 0);
    }
}

// ---------------------------------------------------------------------------
extern "C" void kernel_launch(void* const* d_in, const int* in_sizes, int n_in,
                              void* d_out, int out_size, void* d_ws, size_t ws_size,
                              hipStream_t stream)
{
    (void)in_sizes; (void)n_in; (void)out_size;
    const float* text  = (const float*)d_in[0];
    const float* image = (const float*)d_in[1];
    const float* Wq = (const float*)d_in[2];
    const float* bq = (const float*)d_in[3];
    const float* Wk = (const float*)d_in[4];
    const float* bk = (const float*)d_in[5];
    const float* Wv = (const float*)d_in[6];
    const float* bv = (const float*)d_in[7];
    const float* Wo = (const float*)d_in[8];
    const float* bo = (const float*)d_in[9];
    const float* W1 = (const float*)d_in[10];
    const float* b1 = (const float*)d_in[11];
    const float* W2 = (const float*)d_in[12];
    const float* b2 = (const float*)d_in[13];
    float* out = (float*)d_out;

    const size_t SZ   = (size_t)NB * SL * DM;   // 4,194,304
    const size_t HALF = SZ;

    // ---- fixed workspace layout (bf16 = ushort), ~82.1 MB ----
    ushort* xbf = (ushort*)d_ws;        // [8192,1024] text 0..4095, image 4096..
    ushort* Qb  = xbf + 2*SZ;           // [16,NH,SL,DH]
    ushort* Kb  = Qb  + 2*SZ;           // [16,NH,SL,DH]; later bf16 text_cross
    ushort* VT  = Kb  + 2*SZ;           // [16,NH,DH,SL]
    ushort* AOt = VT  + 2*SZ;           // [4096,1024]
    ushort* Wt  = AOt + SZ;             // Wq^T|Wk^T|Wv^T, later W1^T (fallback)
    float*  RS  = (float*)(Wt + 3*DM*DM);   // [8,NH,SL]
    char*   wsEnd = (char*)(RS + NB*NH*SL);
    ushort* hidden = Qb;                // reuses Q (dead after mid_k)

    float* text_cross = out;            // Wo gemm writes rows 0..8191 (both)
    float* comp       = out + 2*SZ;
    float* avga       = out + 3*SZ;

    // ---- scratch tiers ----
    // tier A (round-7 proven): RS2, WoT, AOi, W2T in ws
    // tier B (round-8 proven): + W1T slot -> W1/W2 transposes fold into prep_k
    const size_t extA = (size_t)NB*NH*SL*4 + (size_t)DM*DM*2
                      + (size_t)SZ*2 + (size_t)DM*DM*2;
    const size_t extB = extA + (size_t)3*DM*DM*2;
    const size_t fixBytes = (size_t)(wsEnd - (char*)d_ws);
    float* RS2; ushort* WoT; ushort* AOi; ushort* W2T; ushort* W1Tx;
    const bool haveA = (ws_size >= fixBytes + extA);
    const bool haveB = (ws_size >= fixBytes + extB);
    if (haveA) {
        RS2 = (float*)wsEnd;
        WoT = (ushort*)(RS2 + NB*NH*SL);
        AOi = WoT + DM*DM;
        W2T = AOi + SZ;
        W1Tx = haveB ? (W2T + DM*DM) : Wt;
    } else {                            // fallback (correctness-first)
        WoT = (ushort*)comp;
        AOi = WoT + DM*DM;
        RS2 = (float*)Wt;
        W2T = AOt;                      // dead after Wo gemm (inside mid_k)
        W1Tx = Wt;
    }

    const dim3 blk(256);

    // ---- prep: cvt + Wq/Wk/Wv/Wo transposes [+ W1/W2 when tier B] ----
    prep_k<<<haveB ? 10240 : 9216, blk, 0, stream>>>(
        text, image, Wq, Wk, Wv, Wo, W1, W2, xbf, Wt, WoT, W1Tx, W2T);

    // ---- fused Q/K/V projection: M=8192, N=3072 ----
    mfma_gemm<0,4,4><<<dim3(24,64), blk, 0, stream>>>(
        xbf, xbf, nullptr, nullptr, DM, DM, DM, DM, DM, nullptr, 0,
        Wt, DM, bq, bk, bv, nullptr, Qb, Kb, VT, 1);

    // ---- both attention directions (1D grid, XCD-pair swizzle) ----
    attn2m_k<<<dim3(1024), blk, 0, stream>>>(Qb, Kb, VT, AOt, AOi, RS, RS2);

    // ---- mid: avg3 (odd) interleaved with Wo gemm (even) ----
    mid_k<<<1024, blk, 0, stream>>>(AOt, AOi, WoT, bo, text_cross, Kb,
                                    Qb, Kb + HALF, RS, avga);
    if (!haveB)   // W1/W2 transposes not folded into prep
        tconvW12_k<<<1024, blk, 0, stream>>>(W1, W2, W1Tx, W2T);

    // ---- MLP (8-wave GEMMs: 512 thr -> 2 waves/SIMD at 1 block/CU) ----
    mfma_gemm<2,2,8><<<dim3(8,32), dim3(512), 0, stream>>>(
        xbf, xbf + SZ, nullptr, Kb, DM, 2*DM, 3*DM, DM, DM, nullptr, 0,
        W1Tx, 3*DM, b1, nullptr, nullptr, nullptr, hidden, nullptr, nullptr, 0);
    mfma_gemm<0,0,8><<<dim3(8,32), dim3(512), 0, stream>>>(
        hidden, hidden, nullptr, nullptr, DM, DM, DM, DM, DM, nullptr, 0,
        W2T, DM, b2, nullptr, nullptr, comp, nullptr, nullptr, nullptr, 0);
}